// Round 7
// baseline (5560.382 us; speedup 1.0000x reference)
//
#include <hip/hip_runtime.h>
#include <math.h>

#define LN2F 0.69314718055994530942f
#define PI_F 3.14159265358979323846f
constexpr float DMU = 4.0f/49.0f;          // gaussian spacing, linspace(0,4,50)
constexpr float GC  = -0.5f/(DMU*DMU);     // smearing coeff

typedef __bf16 bf16x8 __attribute__((ext_vector_type(8)));
typedef float  f32x4  __attribute__((ext_vector_type(4)));

__device__ __forceinline__ float sspf(float x){
  return fmaxf(x, 0.f) + __logf(1.f + __expf(-fabsf(x))) - LN2F;
}
__device__ __forceinline__ float sigf(float x){
  return __builtin_amdgcn_rcpf(1.f + __expf(-x));
}

// ---------------------------------------------------------------------------
// fp32 GEMM (node-level): out[M,NN] = epi( A'[M,KK] @ B[KK,NN] )
// ---------------------------------------------------------------------------
template<int KK,int NN,bool TRB,int ATR,bool BIAS,int OTR,bool RES>
__global__ __launch_bounds__(256) void gemm_k(
    const float* __restrict__ A, int lda,
    const float* __restrict__ aux, const float* __restrict__ auxvec,
    const float* __restrict__ B, int Kreal, int Nreal,
    const float* __restrict__ bias, const float* __restrict__ res,
    const float* __restrict__ oaux, float* __restrict__ out, int M)
{
  constexpr int TM = 128, BK = 32;
  constexpr int TX = (NN==128)?16:8;
  constexpr int RT = (NN==128)?8:4;
  __shared__ float As[BK][TM+4];
  __shared__ float Bs[BK][NN+4];
  const int t = threadIdx.x;
  const int tx = t % TX, ty = t / TX;
  const int m0 = blockIdx.x * TM;
  float acc[RT][8];
  #pragma unroll
  for (int i=0;i<RT;i++)
    #pragma unroll
    for (int j=0;j<8;j++) acc[i][j]=0.f;

  for (int kc=0; kc<KK; kc+=BK){
    #pragma unroll
    for (int j=0;j<4;j++){
      int p = t + j*256;
      int m = p >> 3;
      int kv = (p & 7) << 2;
      float4 v = make_float4(0.f,0.f,0.f,0.f);
      if (m0+m < M){
        v = *(const float4*)(A + (size_t)(m0+m)*lda + kc + kv);
        if constexpr (ATR==1){ v.x=sspf(v.x); v.y=sspf(v.y); v.z=sspf(v.z); v.w=sspf(v.w); }
        else if constexpr (ATR==2){
          float4 av = *(const float4*)(aux + (size_t)(m0+m)*lda + kc + kv);
          v.x*=sigf(av.x); v.y*=sigf(av.y); v.z*=sigf(av.z); v.w*=sigf(av.w);
        }
        else if constexpr (ATR==3){
          int kg = kc+kv;
          v.x = auxvec[kg+0]*sigf(v.x); v.y = auxvec[kg+1]*sigf(v.y);
          v.z = auxvec[kg+2]*sigf(v.z); v.w = auxvec[kg+3]*sigf(v.w);
        }
      }
      As[kv+0][m]=v.x; As[kv+1][m]=v.y; As[kv+2][m]=v.z; As[kv+3][m]=v.w;
    }
    if constexpr (!TRB){
      #pragma unroll
      for (int j=0;j<(BK*NN)/1024;j++){
        int p = t + j*256;
        int k = p / (NN/4);
        int nv = (p % (NN/4)) << 2;
        float4 v = make_float4(0.f,0.f,0.f,0.f);
        if (kc + k < Kreal) v = *(const float4*)(B + (size_t)(kc+k)*NN + nv);
        *(float4*)&Bs[k][nv] = v;
      }
    } else {
      #pragma unroll
      for (int j=0;j<(BK*NN)/1024;j++){
        int p = t + j*256;
        int n = p >> 3;
        int kv = (p & 7) << 2;
        float4 v = make_float4(0.f,0.f,0.f,0.f);
        if (n < Nreal) v = *(const float4*)(B + (size_t)n*KK + kc + kv);
        Bs[kv+0][n]=v.x; Bs[kv+1][n]=v.y; Bs[kv+2][n]=v.z; Bs[kv+3][n]=v.w;
      }
    }
    __syncthreads();
    #pragma unroll
    for (int k=0;k<BK;k++){
      float a[RT], b[8];
      #pragma unroll
      for (int i=0;i<RT;i+=4) *(float4*)&a[i] = *(const float4*)&As[k][ty*RT+i];
      *(float4*)&b[0] = *(const float4*)&Bs[k][tx*8];
      *(float4*)&b[4] = *(const float4*)&Bs[k][tx*8+4];
      #pragma unroll
      for (int i=0;i<RT;i++)
        #pragma unroll
        for (int j=0;j<8;j++)
          acc[i][j] = fmaf(a[i], b[j], acc[i][j]);
    }
    __syncthreads();
  }
  #pragma unroll
  for (int i=0;i<RT;i++){
    int r = m0 + ty*RT + i;
    if (r < M){
      float vo[8];
      #pragma unroll
      for (int j=0;j<8;j++){
        float v = acc[i][j];
        int c = tx*8 + j;
        if constexpr (BIAS) v += bias[c];
        if constexpr (OTR==1) v = sspf(v);
        else if constexpr (OTR==2) v *= sigf(oaux[(size_t)r*NN + c]);
        if constexpr (RES) v += res[(size_t)r*NN + c];
        vo[j] = v;
      }
      *(float4*)(out + (size_t)r*NN + tx*8)     = make_float4(vo[0],vo[1],vo[2],vo[3]);
      *(float4*)(out + (size_t)r*NN + tx*8 + 4) = make_float4(vo[4],vo[5],vo[6],vo[7]);
    }
  }
}

// ---- counting sort helpers ----
__global__ void hist_k(const int* __restrict__ idx, int* __restrict__ hist, int E){
  int e = blockIdx.x*256 + threadIdx.x;
  if (e<E) atomicAdd(&hist[idx[e]], 1);
}
__global__ void scan_k(const int* __restrict__ cnt, int* __restrict__ out, int n){
  __shared__ int buf[2][1024];
  __shared__ int carry_s;
  if (threadIdx.x==0){ carry_s = 0; out[0] = 0; }
  __syncthreads();
  for (int base=0; base<n; base+=1024){
    int i = base + (int)threadIdx.x;
    int v = (i<n)? cnt[i]:0;
    buf[0][threadIdx.x] = v;
    __syncthreads();
    int src=0;
    for (int off=1; off<1024; off<<=1){
      int val = buf[src][threadIdx.x];
      if ((int)threadIdx.x >= off) val += buf[src][threadIdx.x-off];
      buf[1-src][threadIdx.x] = val;
      src = 1-src;
      __syncthreads();
    }
    int inc = buf[src][threadIdx.x];
    int carry = carry_s;
    if (i < n) out[i+1] = carry + inc;
    __syncthreads();
    if (threadIdx.x == 1023) carry_s = carry + buf[src][1023];
    __syncthreads();
  }
}
__global__ void scatter_k(const int* __restrict__ idx, int* __restrict__ cursor,
                          int* __restrict__ outidx, int E){
  int e = blockIdx.x*256 + threadIdx.x;
  if (e<E){ int p = atomicAdd(&cursor[idx[e]], 1); outidx[p]=e; }
}

// ---------------------------------------------------------------------------
// Fused FORWARD edge kernel, edges in COL-sorted order (sidx).
//   ea(w) -> s1=ssp(ea@W1+b1) -> Wf=s1@W2+b2 ->
//   LDS-accumulate xh[row]*Wf*C per distinct col -> few global atomics.
// ---------------------------------------------------------------------------
__global__ __launch_bounds__(256,3) void fwd_edge_k(
    const float* __restrict__ wv, const float* __restrict__ Cv,
    const int* __restrict__ ei, const int* __restrict__ sidx, int E,
    const __bf16* __restrict__ W1t, const float* __restrict__ b1,
    const __bf16* __restrict__ W2t, const float* __restrict__ b2,
    const float* __restrict__ xh, float* __restrict__ agg)
{
  __shared__ __align__(16) __bf16 s1t[64][136];    // 17.4 KB
  __shared__ float accL[64][128];                  // 32 KB
  __shared__ float wrow[64], Ce[64];
  __shared__ int gi[64], slotA[64], segKey[64];
  __shared__ int ndS;
  const int t = threadIdx.x;
  const int e0 = blockIdx.x*64;

  if (t < 64){
    int j = e0 + t;
    bool ok = j < E;
    int e = ok ? sidx[j] : sidx[E-1];
    wrow[t] = wv[e];
    Ce[t]   = ok ? Cv[e] : 0.f;
    gi[t]   = ei[e];          // gather node (row)
    int key = ei[E+e];        // scatter node (col), sorted
    int kp = __shfl_up(key, 1);
    int flag = (t>0 && key != kp) ? 1 : 0;
    unsigned long long mask = __ballot(flag);
    int sl = (int)__popcll(mask & ((2ull<<t)-1ull));
    slotA[t] = sl;
    if (flag || t==0) segKey[sl] = key;
    if (t==63) ndS = sl+1;
  }
  #pragma unroll
  for (int p=t; p<64*128; p+=256) ((float*)accL)[p] = 0.f;
  __syncthreads();

  const int wid = t>>6, lane = t&63, quad = lane>>4, ln = lane&15;
  f32x4 acc[8];
  #pragma unroll
  for (int nt=0;nt<8;nt++) acc[nt] = (f32x4){0.f,0.f,0.f,0.f};

  // ---- GEMM1: t1 = ea @ W1 ----
  const float wa = wrow[wid*16 + ln];
  #pragma unroll
  for (int ks=0; ks<64; ks+=32){
    bf16x8 a;
    #pragma unroll
    for (int j=0;j<8;j++){
      int k = ks + quad*8 + j;
      float d = wa - (float)k*DMU;
      a[j] = (k<50) ? (__bf16)__expf(GC*d*d) : (__bf16)0.f;
    }
    #pragma unroll
    for (int nt=0; nt<8; nt++){
      bf16x8 b = *(const bf16x8*)(W1t + (size_t)(nt*16+ln)*64 + ks + quad*8);
      acc[nt] = __builtin_amdgcn_mfma_f32_16x16x32_bf16(a, b, acc[nt], 0, 0, 0);
    }
  }
  #pragma unroll
  for (int nt=0; nt<8; nt++){
    int c = nt*16 + ln;
    float bb = b1[c];
    #pragma unroll
    for (int reg=0; reg<4; reg++){
      int r = wid*16 + quad*4 + reg;
      s1t[r][c] = (__bf16)sspf(acc[nt][reg] + bb);
    }
  }
  __syncthreads();

  // ---- GEMM2: Wf = s1 @ W2 (B from global) ----
  #pragma unroll
  for (int nt=0;nt<8;nt++) acc[nt] = (f32x4){0.f,0.f,0.f,0.f};
  #pragma unroll
  for (int ks=0; ks<128; ks+=32){
    bf16x8 a = *(const bf16x8*)&s1t[wid*16 + ln][ks + quad*8];
    #pragma unroll
    for (int nt=0; nt<8; nt++){
      bf16x8 b = *(const bf16x8*)(W2t + (size_t)(nt*16+ln)*128 + ks + quad*8);
      acc[nt] = __builtin_amdgcn_mfma_f32_16x16x32_bf16(a, b, acc[nt], 0, 0, 0);
    }
  }

  // ---- LDS-accumulate scatter ----
  #pragma unroll
  for (int reg=0; reg<4; reg++){
    int r = wid*16 + quad*4 + reg;
    int j = e0 + r;
    if (j < E){
      float ce = Ce[r];
      size_t ri = (size_t)gi[r]*128;
      int sl = slotA[r];
      #pragma unroll
      for (int nt=0; nt<8; nt++){
        int c = nt*16 + ln;
        float wf = acc[nt][reg] + b2[c];
        atomicAdd(&accL[sl][c], xh[ri + c]*ce*wf);
      }
    }
  }
  __syncthreads();
  int nd = ndS;
  for (int p=t; p<nd*128; p+=256){
    int sl = p>>7, c = p&127;
    atomicAdd(&agg[(size_t)segKey[sl]*128 + c], accL[sl][c]);
  }
}

// ---------------------------------------------------------------------------
// Fused BACKWARD edge kernel, edges in ROW-sorted order (sidx).
//   recompute t1/sig/s1 -> Wf -> (dC, LDS-accumulated dxh, dWf) ->
//   dt1=dWf@W2^T*sig -> dea=dt1@W1^T -> dw contraction.
// ---------------------------------------------------------------------------
__global__ __launch_bounds__(256,3) void bwd_edge_k(
    const float* __restrict__ wv, const float* __restrict__ Cv,
    const int* __restrict__ ei, const int* __restrict__ sidx, int E,
    const __bf16* __restrict__ W1t, const float* __restrict__ b1,
    const __bf16* __restrict__ W2t, const float* __restrict__ b2,
    const __bf16* __restrict__ W2c, const __bf16* __restrict__ W1c,
    const float* __restrict__ dagg, const float* __restrict__ xh,
    float* __restrict__ dxh, float* __restrict__ dC, float* __restrict__ dw,
    int accum)
{
  __shared__ __align__(16) __bf16 tb[64][136];     // 17.4 KB
  __shared__ float accL[64][128];                  // 32 KB
  __shared__ float wrow[64], Ce[64];
  __shared__ int gi[64], ci64[64], slotA[64], segKey[64], origE[64];
  __shared__ int ndS;
  const int t = threadIdx.x;
  const int e0 = blockIdx.x*64;

  if (t < 64){
    int j = e0 + t;
    bool ok = j < E;
    int e = ok ? sidx[j] : sidx[E-1];
    origE[t] = e;
    wrow[t] = wv[e];
    Ce[t]   = ok ? Cv[e] : 0.f;
    int key = ei[e];          // row (sorted) = gather xh / scatter dxh
    ci64[t] = ei[E+e];        // col = gather dagg
    gi[t]   = key;
    int kp = __shfl_up(key, 1);
    int flag = (t>0 && key != kp) ? 1 : 0;
    unsigned long long mask = __ballot(flag);
    int sl = (int)__popcll(mask & ((2ull<<t)-1ull));
    slotA[t] = sl;
    if (flag || t==0) segKey[sl] = key;
    if (t==63) ndS = sl+1;
  }
  #pragma unroll
  for (int p=t; p<64*128; p+=256) ((float*)accL)[p] = 0.f;
  __syncthreads();

  const int wid = t>>6, lane = t&63, quad = lane>>4, ln = lane&15;
  f32x4 acc[8];
  float sig[8][4];
  #pragma unroll
  for (int nt=0;nt<8;nt++) acc[nt] = (f32x4){0.f,0.f,0.f,0.f};

  // ---- GEMM1: t1 = ea @ W1 ; keep sig(t1), store ssp(t1) ----
  const float wa = wrow[wid*16 + ln];
  #pragma unroll
  for (int ks=0; ks<64; ks+=32){
    bf16x8 a;
    #pragma unroll
    for (int j=0;j<8;j++){
      int k = ks + quad*8 + j;
      float d = wa - (float)k*DMU;
      a[j] = (k<50) ? (__bf16)__expf(GC*d*d) : (__bf16)0.f;
    }
    #pragma unroll
    for (int nt=0; nt<8; nt++){
      bf16x8 b = *(const bf16x8*)(W1t + (size_t)(nt*16+ln)*64 + ks + quad*8);
      acc[nt] = __builtin_amdgcn_mfma_f32_16x16x32_bf16(a, b, acc[nt], 0, 0, 0);
    }
  }
  #pragma unroll
  for (int nt=0; nt<8; nt++){
    int c = nt*16 + ln;
    float bb = b1[c];
    #pragma unroll
    for (int reg=0; reg<4; reg++){
      int r = wid*16 + quad*4 + reg;
      float t1 = acc[nt][reg] + bb;
      sig[nt][reg] = sigf(t1);
      tb[r][c] = (__bf16)sspf(t1);
    }
  }
  __syncthreads();

  // ---- GEMM2: Wf = s1 @ W2 ----
  #pragma unroll
  for (int nt=0;nt<8;nt++) acc[nt] = (f32x4){0.f,0.f,0.f,0.f};
  #pragma unroll
  for (int ks=0; ks<128; ks+=32){
    bf16x8 a = *(const bf16x8*)&tb[wid*16 + ln][ks + quad*8];
    #pragma unroll
    for (int nt=0; nt<8; nt++){
      bf16x8 b = *(const bf16x8*)(W2t + (size_t)(nt*16+ln)*128 + ks + quad*8);
      acc[nt] = __builtin_amdgcn_mfma_f32_16x16x32_bf16(a, b, acc[nt], 0, 0, 0);
    }
  }
  __syncthreads();   // reads of tb (s1) done

  // ---- edge step: dC, dxh -> LDS accum, dWf -> tb ----
  #pragma unroll
  for (int reg=0; reg<4; reg++){
    int r = wid*16 + quad*4 + reg;
    int j = e0 + r;
    float dcp = 0.f;
    if (j < E){
      float ce = Ce[r];
      size_t ri = (size_t)gi[r]*128;
      size_t cc = (size_t)ci64[r]*128;
      int sl = slotA[r];
      #pragma unroll
      for (int nt=0; nt<8; nt++){
        int c = nt*16 + ln;
        float wf = acc[nt][reg] + b2[c];
        float da = dagg[cc + c];
        float xv = xh[ri + c];
        dcp += da*xv*wf;
        atomicAdd(&accL[sl][c], da*ce*wf);
        tb[r][c] = (__bf16)(da*xv*ce);
      }
    } else {
      #pragma unroll
      for (int nt=0; nt<8; nt++) tb[r][nt*16+ln] = (__bf16)0.f;
    }
    dcp += __shfl_xor(dcp, 1);
    dcp += __shfl_xor(dcp, 2);
    dcp += __shfl_xor(dcp, 4);
    dcp += __shfl_xor(dcp, 8);
    if (ln==0 && j < E){
      int e = origE[r];
      dC[e] = accum ? (dC[e]+dcp) : dcp;
    }
  }
  __syncthreads();

  // flush dxh LDS accumulator
  {
    int nd = ndS;
    for (int p=t; p<nd*128; p+=256){
      int sl = p>>7, c = p&127;
      atomicAdd(&dxh[(size_t)segKey[sl]*128 + c], accL[sl][c]);
    }
  }

  // ---- GEMM3: dt1 = (dWf @ W2^T) * sig ----
  #pragma unroll
  for (int nt=0;nt<8;nt++) acc[nt] = (f32x4){0.f,0.f,0.f,0.f};
  #pragma unroll
  for (int ks=0; ks<128; ks+=32){
    bf16x8 a = *(const bf16x8*)&tb[wid*16 + ln][ks + quad*8];
    #pragma unroll
    for (int nt=0; nt<8; nt++){
      bf16x8 b = *(const bf16x8*)(W2c + (size_t)(nt*16+ln)*128 + ks + quad*8);
      acc[nt] = __builtin_amdgcn_mfma_f32_16x16x32_bf16(a, b, acc[nt], 0, 0, 0);
    }
  }
  __syncthreads();   // reads of tb (dWf) done
  #pragma unroll
  for (int nt=0; nt<8; nt++){
    int c = nt*16 + ln;
    #pragma unroll
    for (int reg=0; reg<4; reg++){
      int r = wid*16 + quad*4 + reg;
      tb[r][c] = (__bf16)(acc[nt][reg] * sig[nt][reg]);
    }
  }
  __syncthreads();

  // ---- GEMM4: dea = dt1 @ W1^T ; contract to dw ----
  #pragma unroll
  for (int nt=0;nt<4;nt++) acc[nt] = (f32x4){0.f,0.f,0.f,0.f};
  #pragma unroll
  for (int ks=0; ks<128; ks+=32){
    bf16x8 a = *(const bf16x8*)&tb[wid*16 + ln][ks + quad*8];
    #pragma unroll
    for (int nt=0; nt<4; nt++){
      bf16x8 b = *(const bf16x8*)(W1c + (size_t)(nt*16+ln)*128 + ks + quad*8);
      acc[nt] = __builtin_amdgcn_mfma_f32_16x16x32_bf16(a, b, acc[nt], 0, 0, 0);
    }
  }
  #pragma unroll
  for (int reg=0; reg<4; reg++){
    int r = wid*16 + quad*4 + reg;
    int j = e0 + r;
    float w = wrow[r];
    float s = 0.f;
    #pragma unroll
    for (int nt=0; nt<4; nt++){
      int c = nt*16 + ln;
      if (c < 50){
        float d = w - (float)c*DMU;
        s += acc[nt][reg] * (2.f*GC*d) * __expf(GC*d*d);
      }
    }
    s += __shfl_xor(s, 1);
    s += __shfl_xor(s, 2);
    s += __shfl_xor(s, 4);
    s += __shfl_xor(s, 8);
    if (ln==0 && j < E){
      int e = origE[r];
      dw[e] = accum ? (dw[e]+s) : s;
    }
  }
}

// ---------------------------------------------------------------------------
// one-time bf16 weight conversion
// ---------------------------------------------------------------------------
__global__ void convw_k(const float* __restrict__ w1, const float* __restrict__ w2,
                        __bf16* __restrict__ W1t, __bf16* __restrict__ W2t,
                        __bf16* __restrict__ W2c, __bf16* __restrict__ W1c, int total)
{
  int idx = blockIdx.x*256 + threadIdx.x;
  if (idx >= total) return;
  int l = idx / 49152;
  int r = idx % 49152;
  if (r < 8192){                       // W1t[n][k] = w1[k][n], k<50
    int n = r / 64, k = r % 64;
    float v = (k<50) ? w1[(size_t)l*6400 + k*128 + n] : 0.f;
    W1t[(size_t)l*8192 + r] = (__bf16)v;
  } else if (r < 24576){               // W2t[n][k] = w2[k][n]
    int r2 = r - 8192;
    int n = r2 / 128, k = r2 % 128;
    W2t[(size_t)l*16384 + r2] = (__bf16)w2[(size_t)l*16384 + k*128 + n];
  } else if (r < 40960){               // W2c = w2 (elementwise)
    int r2 = r - 24576;
    W2c[(size_t)l*16384 + r2] = (__bf16)w2[(size_t)l*16384 + r2];
  } else {                             // W1c[n][k] = w1[n][k], n<50
    int r2 = r - 40960;
    int n = r2 / 128, k = r2 % 128;
    float v = (n<50) ? w1[(size_t)l*6400 + n*128 + k] : 0.f;
    W1c[(size_t)l*8192 + r2] = (__bf16)v;
  }
}

// ---------------------------------------------------------------------------
__global__ void edge_geom_k(const float* __restrict__ pos, const int* __restrict__ ei,
                            const float* __restrict__ off, const float* __restrict__ cell,
                            float* __restrict__ wv, float* __restrict__ Cv, int E)
{
  int e = blockIdx.x*256 + threadIdx.x;
  if (e>=E) return;
  int r = ei[e], c = ei[E+e];
  float o0=off[3*e], o1=off[3*e+1], o2=off[3*e+2];
  float d0 = o0*cell[0] + o1*cell[3] + o2*cell[6];
  float d1 = o0*cell[1] + o1*cell[4] + o2*cell[7];
  float d2 = o0*cell[2] + o1*cell[5] + o2*cell[8];
  float v0 = pos[3*r+0]-pos[3*c+0]+d0;
  float v1 = pos[3*r+1]-pos[3*c+1]+d1;
  float v2 = pos[3*r+2]-pos[3*c+2]+d2;
  float w = sqrtf(v0*v0+v1*v1+v2*v2);
  wv[e]=w;
  Cv[e]=0.5f*cosf(w*(PI_F/4.0f)) + 0.5f;
}

__global__ void embed_k(const float* __restrict__ emb, const int* __restrict__ z,
                        float* __restrict__ h, int total){
  int i = blockIdx.x*256 + threadIdx.x;
  if (i < total){ int n=i>>7, j=i&127; h[i] = emb[(size_t)z[n]*128 + j]; }
}

// readout energy
__global__ void head_k(const float* __restrict__ u, const float* __restrict__ o2,
                       const float* __restrict__ o2b, float* __restrict__ out0, int N){
  int n = blockIdx.x*256 + threadIdx.x;
  float s = 0.f;
  if (n < N){
    #pragma unroll
    for (int k=0;k<64;k+=4){
      float4 uv = *(const float4*)(u + (size_t)n*64 + k);
      float4 ov = *(const float4*)(o2 + k);
      s += sspf(uv.x)*ov.x + sspf(uv.y)*ov.y + sspf(uv.z)*ov.z + sspf(uv.w)*ov.w;
    }
  }
  #pragma unroll
  for (int m=1;m<64;m<<=1) s += __shfl_xor(s, m);
  __shared__ float red[4];
  int lane = threadIdx.x&63, w = threadIdx.x>>6;
  if (lane==0) red[w]=s;
  __syncthreads();
  if (threadIdx.x==0){
    float tot = red[0]+red[1]+red[2]+red[3];
    if (blockIdx.x==0) tot += (float)N * o2b[0];
    atomicAdd(out0, tot);
  }
}

// forces: recompute vec, dvec = vec*(dw + dC*dCdw)/w, atomic scatter to f
__global__ void force_k(const float* __restrict__ dw, const float* __restrict__ dC,
                        const float* __restrict__ wv,
                        const float* __restrict__ pos, const int* __restrict__ ei,
                        const float* __restrict__ off, const float* __restrict__ cell,
                        float* __restrict__ f, int E)
{
  int e = blockIdx.x*256 + threadIdx.x;
  if (e>=E) return;
  int r = ei[e], c = ei[E+e];
  float o0=off[3*e], o1=off[3*e+1], o2=off[3*e+2];
  float d0 = o0*cell[0] + o1*cell[3] + o2*cell[6];
  float d1 = o0*cell[1] + o1*cell[4] + o2*cell[7];
  float d2 = o0*cell[2] + o1*cell[5] + o2*cell[8];
  float v0 = pos[3*r+0]-pos[3*c+0]+d0;
  float v1 = pos[3*r+1]-pos[3*c+1]+d1;
  float v2 = pos[3*r+2]-pos[3*c+2]+d2;
  float w = wv[e];
  float dwt = dw[e] + dC[e] * (-0.5f*(PI_F/4.0f)) * __sinf(w*(PI_F/4.0f));
  float s = dwt / w;
  atomicAdd(&f[3*r+0], -v0*s); atomicAdd(&f[3*r+1], -v1*s); atomicAdd(&f[3*r+2], -v2*s);
  atomicAdd(&f[3*c+0],  v0*s); atomicAdd(&f[3*c+1],  v1*s); atomicAdd(&f[3*c+2],  v2*s);
}

// ---------------------------------------------------------------------------
extern "C" void kernel_launch(void* const* d_in, const int* in_sizes, int n_in,
                              void* d_out, int out_size, void* d_ws, size_t ws_size,
                              hipStream_t stream)
{
  const int N = in_sizes[0];
  const int E = in_sizes[2]/2;
  const int L = 6;
  const int* z        = (const int*)d_in[0];
  const float* pos    = (const float*)d_in[1];
  const int* ei       = (const int*)d_in[2];
  const float* offset = (const float*)d_in[3];
  const float* cell   = (const float*)d_in[4];
  const float* emb    = (const float*)d_in[5];
  const float* mlp_w1 = (const float*)d_in[6];
  const float* mlp_b1 = (const float*)d_in[7];
  const float* mlp_w2 = (const float*)d_in[8];
  const float* mlp_b2 = (const float*)d_in[9];
  const float* conv_w1= (const float*)d_in[10];
  const float* conv_w2= (const float*)d_in[11];
  const float* conv_b2= (const float*)d_in[12];
  const float* lin_w  = (const float*)d_in[13];
  const float* lin_b  = (const float*)d_in[14];
  const float* out1_w = (const float*)d_in[15];
  const float* out1_b = (const float*)d_in[16];
  const float* out2_w = (const float*)d_in[17];
  const float* out2_b = (const float*)d_in[18];
  float* out = (float*)d_out;

  char* wp = (char*)d_ws;
  auto alloc = [&](size_t bytes)->char*{ char* p = wp; wp += (bytes + 255) & ~(size_t)255; return p; };
  float* wbuf = (float*)alloc((size_t)E*4);
  float* Cbuf = (float*)alloc((size_t)E*4);
  float* dCb  = (float*)alloc((size_t)E*4);
  float* dwb  = (float*)alloc((size_t)E*4);
  float* xh   = (float*)alloc((size_t)L*N*128*4);
  float* mbuf = (float*)alloc((size_t)L*N*128*4);
  float* ubuf = (float*)alloc((size_t)N*64*4);
  float* hbuf = (float*)alloc((size_t)N*128*4);
  float* Gbuf = (float*)alloc((size_t)N*128*4);
  float* bufA = (float*)alloc((size_t)N*128*4);
  float* bufB = (float*)alloc((size_t)N*128*4);
  float* bufC = (float*)alloc((size_t)N*128*4);   // dxh
  float* aggb = (float*)alloc((size_t)N*128*4);
  __bf16* W1t = (__bf16*)alloc((size_t)L*8192*2);
  __bf16* W2t = (__bf16*)alloc((size_t)L*16384*2);
  __bf16* W2c = (__bf16*)alloc((size_t)L*16384*2);
  __bf16* W1c = (__bf16*)alloc((size_t)L*8192*2);
  // counting-sort buffers
  int* histb    = (int*)alloc((size_t)N*4);
  int* colstart = (int*)alloc((size_t)(N+1)*4);
  int* rowstart = (int*)alloc((size_t)(N+1)*4);
  int* colidx   = (int*)alloc((size_t)E*4);
  int* rowidx   = (int*)alloc((size_t)E*4);
  int* cursor   = (int*)alloc((size_t)N*4);

  const int egrid = (E+255)/256;
  const int eg64 = (E+63)/64;
  const int ng = (N+127)/128;
  const int wtotal = L*49152;

  hipMemsetAsync(d_out, 0, (size_t)out_size*4, stream);
  convw_k<<<(wtotal+255)/256,256,0,stream>>>(mlp_w1, mlp_w2, W1t, W2t, W2c, W1c, wtotal);
  edge_geom_k<<<egrid,256,0,stream>>>(pos, ei, offset, cell, wbuf, Cbuf, E);
  embed_k<<<(N*128+255)/256,256,0,stream>>>(emb, z, hbuf, N*128);

  // counting sorts: col-sorted (forward scatter) and row-sorted (backward)
  hipMemsetAsync(histb, 0, (size_t)N*4, stream);
  hist_k<<<egrid,256,0,stream>>>(ei+E, histb, E);
  scan_k<<<1,1024,0,stream>>>(histb, colstart, N);
  hipMemcpyAsync(cursor, colstart, (size_t)N*4, hipMemcpyDeviceToDevice, stream);
  scatter_k<<<egrid,256,0,stream>>>(ei+E, cursor, colidx, E);
  hipMemsetAsync(histb, 0, (size_t)N*4, stream);
  hist_k<<<egrid,256,0,stream>>>(ei, histb, E);
  scan_k<<<1,1024,0,stream>>>(histb, rowstart, N);
  hipMemcpyAsync(cursor, rowstart, (size_t)N*4, hipMemcpyDeviceToDevice, stream);
  scatter_k<<<egrid,256,0,stream>>>(ei, cursor, rowidx, E);

  // ---------------- forward ----------------
  for (int i=0;i<L;i++){
    const float* b1i = mlp_b1 + (size_t)i*128;
    const float* b2i = mlp_b2 + (size_t)i*128;
    const float* cw1i= conv_w1+ (size_t)i*128*128;
    const float* cw2i= conv_w2+ (size_t)i*128*128;
    const float* cb2i= conv_b2+ (size_t)i*128;
    const float* lwi = lin_w  + (size_t)i*128*128;
    const float* lbi = lin_b  + (size_t)i*128;
    float* xhi = xh   + (size_t)i*N*128;
    float* mi  = mbuf + (size_t)i*N*128;

    gemm_k<128,128,false,0,false,0,false><<<ng,256,0,stream>>>(
      hbuf, 128, nullptr, nullptr, cw1i, 128, 128, nullptr, nullptr, nullptr, xhi, N);
    hipMemsetAsync(aggb, 0, (size_t)N*128*4, stream);
    fwd_edge_k<<<eg64,256,0,stream>>>(
      wbuf, Cbuf, ei, colidx, E, W1t + (size_t)i*8192, b1i, W2t + (size_t)i*16384, b2i, xhi, aggb);
    gemm_k<128,128,false,0,true,0,false><<<ng,256,0,stream>>>(
      aggb, 128, nullptr, nullptr, cw2i, 128, 128, cb2i, nullptr, nullptr, mi, N);
    gemm_k<128,128,false,1,true,0,true><<<ng,256,0,stream>>>(
      mi, 128, nullptr, nullptr, lwi, 128, 128, lbi, hbuf, nullptr, hbuf, N);
  }

  // head: u = h@o1+b ; E = sum ssp(u)@o2 + N*o2b ; G = (o2*sig(u))@o1^T
  gemm_k<128,64,false,0,true,0,false><<<ng,256,0,stream>>>(
    hbuf, 128, nullptr, nullptr, out1_w, 128, 64, out1_b, nullptr, nullptr, ubuf, N);
  head_k<<<(N+255)/256,256,0,stream>>>(ubuf, out2_w, out2_b, out, N);
  gemm_k<64,128,true,3,false,0,false><<<ng,256,0,stream>>>(
    ubuf, 64, nullptr, out2_w, out1_w, 64, 128, nullptr, nullptr, nullptr, Gbuf, N);

  // ---------------- backward ----------------
  for (int i=L-1;i>=0;i--){
    const float* b1i = mlp_b1 + (size_t)i*128;
    const float* b2i = mlp_b2 + (size_t)i*128;
    const float* cw1i= conv_w1+ (size_t)i*128*128;
    const float* cw2i= conv_w2+ (size_t)i*128*128;
    const float* lwi = lin_w  + (size_t)i*128*128;
    float* xhi = xh   + (size_t)i*N*128;
    float* mi  = mbuf + (size_t)i*N*128;
    int first = (i==L-1) ? 0 : 1;

    gemm_k<128,128,true,0,false,0,false><<<ng,256,0,stream>>>(
      Gbuf, 128, nullptr, nullptr, lwi, 128, 128, nullptr, nullptr, nullptr, bufA, N);
    gemm_k<128,128,true,2,false,0,false><<<ng,256,0,stream>>>(
      bufA, 128, mi, nullptr, cw2i, 128, 128, nullptr, nullptr, nullptr, bufB, N);
    hipMemsetAsync(bufC, 0, (size_t)N*128*4, stream);
    bwd_edge_k<<<eg64,256,0,stream>>>(
      wbuf, Cbuf, ei, rowidx, E,
      W1t + (size_t)i*8192, b1i, W2t + (size_t)i*16384, b2i,
      W2c + (size_t)i*16384, W1c + (size_t)i*8192,
      bufB, xhi, bufC, dCb, dwb, first);
    gemm_k<128,128,true,0,false,0,true><<<ng,256,0,stream>>>(
      bufC, 128, nullptr, nullptr, cw1i, 128, 128, nullptr, Gbuf, nullptr, Gbuf, N);
  }

  force_k<<<egrid,256,0,stream>>>(dwb, dCb, wbuf, pos, ei, offset, cell, out+1, E);
}

// Round 8
// 5358.715 us; speedup vs baseline: 1.0376x; 1.0376x over previous
//
#include <hip/hip_runtime.h>
#include <math.h>

#define LN2F 0.69314718055994530942f
#define PI_F 3.14159265358979323846f
constexpr float DMU = 4.0f/49.0f;          // gaussian spacing, linspace(0,4,50)
constexpr float GC  = -0.5f/(DMU*DMU);     // smearing coeff

typedef __bf16 bf16x8 __attribute__((ext_vector_type(8)));
typedef float  f32x4  __attribute__((ext_vector_type(4)));

__device__ __forceinline__ float sspf(float x){
  return fmaxf(x, 0.f) + __logf(1.f + __expf(-fabsf(x))) - LN2F;
}
__device__ __forceinline__ float sigf(float x){
  return __builtin_amdgcn_rcpf(1.f + __expf(-x));
}

// ---------------------------------------------------------------------------
// fp32 GEMM (node-level): out[M,NN] = epi( A'[M,KK] @ B[KK,NN] )
// ---------------------------------------------------------------------------
template<int KK,int NN,bool TRB,int ATR,bool BIAS,int OTR,bool RES>
__global__ __launch_bounds__(256) void gemm_k(
    const float* __restrict__ A, int lda,
    const float* __restrict__ aux, const float* __restrict__ auxvec,
    const float* __restrict__ B, int Kreal, int Nreal,
    const float* __restrict__ bias, const float* __restrict__ res,
    const float* __restrict__ oaux, float* __restrict__ out, int M)
{
  constexpr int TM = 128, BK = 32;
  constexpr int TX = (NN==128)?16:8;
  constexpr int RT = (NN==128)?8:4;
  __shared__ float As[BK][TM+4];
  __shared__ float Bs[BK][NN+4];
  const int t = threadIdx.x;
  const int tx = t % TX, ty = t / TX;
  const int m0 = blockIdx.x * TM;
  float acc[RT][8];
  #pragma unroll
  for (int i=0;i<RT;i++)
    #pragma unroll
    for (int j=0;j<8;j++) acc[i][j]=0.f;

  for (int kc=0; kc<KK; kc+=BK){
    #pragma unroll
    for (int j=0;j<4;j++){
      int p = t + j*256;
      int m = p >> 3;
      int kv = (p & 7) << 2;
      float4 v = make_float4(0.f,0.f,0.f,0.f);
      if (m0+m < M){
        v = *(const float4*)(A + (size_t)(m0+m)*lda + kc + kv);
        if constexpr (ATR==1){ v.x=sspf(v.x); v.y=sspf(v.y); v.z=sspf(v.z); v.w=sspf(v.w); }
        else if constexpr (ATR==2){
          float4 av = *(const float4*)(aux + (size_t)(m0+m)*lda + kc + kv);
          v.x*=sigf(av.x); v.y*=sigf(av.y); v.z*=sigf(av.z); v.w*=sigf(av.w);
        }
        else if constexpr (ATR==3){
          int kg = kc+kv;
          v.x = auxvec[kg+0]*sigf(v.x); v.y = auxvec[kg+1]*sigf(v.y);
          v.z = auxvec[kg+2]*sigf(v.z); v.w = auxvec[kg+3]*sigf(v.w);
        }
      }
      As[kv+0][m]=v.x; As[kv+1][m]=v.y; As[kv+2][m]=v.z; As[kv+3][m]=v.w;
    }
    if constexpr (!TRB){
      #pragma unroll
      for (int j=0;j<(BK*NN)/1024;j++){
        int p = t + j*256;
        int k = p / (NN/4);
        int nv = (p % (NN/4)) << 2;
        float4 v = make_float4(0.f,0.f,0.f,0.f);
        if (kc + k < Kreal) v = *(const float4*)(B + (size_t)(kc+k)*NN + nv);
        *(float4*)&Bs[k][nv] = v;
      }
    } else {
      #pragma unroll
      for (int j=0;j<(BK*NN)/1024;j++){
        int p = t + j*256;
        int n = p >> 3;
        int kv = (p & 7) << 2;
        float4 v = make_float4(0.f,0.f,0.f,0.f);
        if (n < Nreal) v = *(const float4*)(B + (size_t)n*KK + kc + kv);
        Bs[kv+0][n]=v.x; Bs[kv+1][n]=v.y; Bs[kv+2][n]=v.z; Bs[kv+3][n]=v.w;
      }
    }
    __syncthreads();
    #pragma unroll
    for (int k=0;k<BK;k++){
      float a[RT], b[8];
      #pragma unroll
      for (int i=0;i<RT;i+=4) *(float4*)&a[i] = *(const float4*)&As[k][ty*RT+i];
      *(float4*)&b[0] = *(const float4*)&Bs[k][tx*8];
      *(float4*)&b[4] = *(const float4*)&Bs[k][tx*8+4];
      #pragma unroll
      for (int i=0;i<RT;i++)
        #pragma unroll
        for (int j=0;j<8;j++)
          acc[i][j] = fmaf(a[i], b[j], acc[i][j]);
    }
    __syncthreads();
  }
  #pragma unroll
  for (int i=0;i<RT;i++){
    int r = m0 + ty*RT + i;
    if (r < M){
      float vo[8];
      #pragma unroll
      for (int j=0;j<8;j++){
        float v = acc[i][j];
        int c = tx*8 + j;
        if constexpr (BIAS) v += bias[c];
        if constexpr (OTR==1) v = sspf(v);
        else if constexpr (OTR==2) v *= sigf(oaux[(size_t)r*NN + c]);
        if constexpr (RES) v += res[(size_t)r*NN + c];
        vo[j] = v;
      }
      *(float4*)(out + (size_t)r*NN + tx*8)     = make_float4(vo[0],vo[1],vo[2],vo[3]);
      *(float4*)(out + (size_t)r*NN + tx*8 + 4) = make_float4(vo[4],vo[5],vo[6],vo[7]);
    }
  }
}

// ---- counting sort helpers ----
__global__ void hist_k(const int* __restrict__ idx, int* __restrict__ hist, int E){
  int e = blockIdx.x*256 + threadIdx.x;
  if (e<E) atomicAdd(&hist[idx[e]], 1);
}
__global__ void scan_k(const int* __restrict__ cnt, int* __restrict__ out, int n){
  __shared__ int buf[2][1024];
  __shared__ int carry_s;
  if (threadIdx.x==0){ carry_s = 0; out[0] = 0; }
  __syncthreads();
  for (int base=0; base<n; base+=1024){
    int i = base + (int)threadIdx.x;
    int v = (i<n)? cnt[i]:0;
    buf[0][threadIdx.x] = v;
    __syncthreads();
    int src=0;
    for (int off=1; off<1024; off<<=1){
      int val = buf[src][threadIdx.x];
      if ((int)threadIdx.x >= off) val += buf[src][threadIdx.x-off];
      buf[1-src][threadIdx.x] = val;
      src = 1-src;
      __syncthreads();
    }
    int inc = buf[src][threadIdx.x];
    int carry = carry_s;
    if (i < n) out[i+1] = carry + inc;
    __syncthreads();
    if (threadIdx.x == 1023) carry_s = carry + buf[src][1023];
    __syncthreads();
  }
}
__global__ void scatter_k(const int* __restrict__ idx, int* __restrict__ cursor,
                          int* __restrict__ outidx, int E){
  int e = blockIdx.x*256 + threadIdx.x;
  if (e<E){ int p = atomicAdd(&cursor[idx[e]], 1); outidx[p]=e; }
}
// reorder edge metadata into sorted order (one-time gather)
__global__ void reorder_k(const int* __restrict__ sidx, const int* __restrict__ ei,
                          const float* __restrict__ wv, const float* __restrict__ Cv,
                          const float* __restrict__ off, int E,
                          int* __restrict__ rowS, int* __restrict__ colS,
                          float* __restrict__ wS, float* __restrict__ CS,
                          float* __restrict__ offS /*nullable*/){
  int j = blockIdx.x*256 + threadIdx.x;
  if (j>=E) return;
  int e = sidx[j];
  rowS[j]=ei[e]; colS[j]=ei[E+e]; wS[j]=wv[e]; CS[j]=Cv[e];
  if (offS){ offS[3*j]=off[3*e]; offS[3*j+1]=off[3*e+1]; offS[3*j+2]=off[3*e+2]; }
}

// ---------------------------------------------------------------------------
// Fused FORWARD edge kernel, edges in COL-sorted order (pre-sorted metadata).
// ---------------------------------------------------------------------------
__global__ __launch_bounds__(256,4) void fwd_edge_k(
    const float* __restrict__ wS, const float* __restrict__ CS,
    const int* __restrict__ rowS, const int* __restrict__ colS, int E,
    const __bf16* __restrict__ W1t, const float* __restrict__ b1,
    const __bf16* __restrict__ W2t, const float* __restrict__ b2,
    const float* __restrict__ xh, float* __restrict__ agg)
{
  __shared__ __align__(16) __bf16 s1t[64][136];    // 17.4 KB
  __shared__ float accL[32][128];                  // 16 KB
  __shared__ float wrow[64], Ce[64];
  __shared__ int gi[64], key64[64], slotA[64], segKey[64];
  __shared__ int ndS;
  const int t = threadIdx.x;
  const int e0 = blockIdx.x*64;

  if (t < 64){
    int j = e0 + t;
    bool ok = j < E;
    int jc = ok ? j : E-1;
    wrow[t] = wS[jc];
    Ce[t]   = ok ? CS[jc] : 0.f;
    gi[t]   = rowS[jc];
    int key = colS[jc];
    key64[t]= key;
    int kp = __shfl_up(key, 1);
    int flag = (t>0 && key != kp) ? 1 : 0;
    unsigned long long mask = __ballot(flag);
    int sl = (int)__popcll(mask & ((2ull<<t)-1ull));
    slotA[t] = sl;
    if ((flag || t==0) && sl < 32) segKey[sl] = key;
    if (t==63) ndS = sl+1;
  }
  #pragma unroll
  for (int p=t; p<32*128; p+=256) ((float*)accL)[p] = 0.f;
  __syncthreads();

  const int wid = t>>6, lane = t&63, quad = lane>>4, ln = lane&15;
  f32x4 acc[8];
  #pragma unroll
  for (int nt=0;nt<8;nt++) acc[nt] = (f32x4){0.f,0.f,0.f,0.f};

  // ---- GEMM1: t1 = ea @ W1 ----
  const float wa = wrow[wid*16 + ln];
  #pragma unroll
  for (int ks=0; ks<64; ks+=32){
    bf16x8 a;
    #pragma unroll
    for (int j=0;j<8;j++){
      int k = ks + quad*8 + j;
      float d = wa - (float)k*DMU;
      a[j] = (k<50) ? (__bf16)__expf(GC*d*d) : (__bf16)0.f;
    }
    #pragma unroll
    for (int nt=0; nt<8; nt++){
      bf16x8 b = *(const bf16x8*)(W1t + (size_t)(nt*16+ln)*64 + ks + quad*8);
      acc[nt] = __builtin_amdgcn_mfma_f32_16x16x32_bf16(a, b, acc[nt], 0, 0, 0);
    }
  }
  #pragma unroll
  for (int nt=0; nt<8; nt++){
    int c = nt*16 + ln;
    float bb = b1[c];
    #pragma unroll
    for (int reg=0; reg<4; reg++){
      int r = wid*16 + quad*4 + reg;
      s1t[r][c] = (__bf16)sspf(acc[nt][reg] + bb);
    }
  }
  __syncthreads();

  // ---- GEMM2: Wf = s1 @ W2 (B from global) ----
  #pragma unroll
  for (int nt=0;nt<8;nt++) acc[nt] = (f32x4){0.f,0.f,0.f,0.f};
  #pragma unroll
  for (int ks=0; ks<128; ks+=32){
    bf16x8 a = *(const bf16x8*)&s1t[wid*16 + ln][ks + quad*8];
    #pragma unroll
    for (int nt=0; nt<8; nt++){
      bf16x8 b = *(const bf16x8*)(W2t + (size_t)(nt*16+ln)*128 + ks + quad*8);
      acc[nt] = __builtin_amdgcn_mfma_f32_16x16x32_bf16(a, b, acc[nt], 0, 0, 0);
    }
  }

  // ---- LDS-accumulate scatter (overflow -> direct atomic) ----
  #pragma unroll
  for (int reg=0; reg<4; reg++){
    int r = wid*16 + quad*4 + reg;
    int j = e0 + r;
    if (j < E){
      float ce = Ce[r];
      size_t ri = (size_t)gi[r]*128;
      int sl = slotA[r];
      if (sl < 32){
        #pragma unroll
        for (int nt=0; nt<8; nt++){
          int c = nt*16 + ln;
          float wf = acc[nt][reg] + b2[c];
          atomicAdd(&accL[sl][c], xh[ri + c]*ce*wf);
        }
      } else {
        size_t ci = (size_t)key64[r]*128;
        #pragma unroll
        for (int nt=0; nt<8; nt++){
          int c = nt*16 + ln;
          float wf = acc[nt][reg] + b2[c];
          atomicAdd(&agg[ci + c], xh[ri + c]*ce*wf);
        }
      }
    }
  }
  __syncthreads();
  int nd = ndS; if (nd > 32) nd = 32;
  for (int p=t; p<nd*128; p+=256){
    int sl = p>>7, c = p&127;
    atomicAdd(&agg[(size_t)segKey[sl]*128 + c], accL[sl][c]);
  }
}

// ---------------------------------------------------------------------------
// Fused BACKWARD edge kernel, edges in ROW-sorted order (pre-sorted metadata).
// dC/dw outputs are in SORTED coordinates (coalesced; force_k consumes same).
// ---------------------------------------------------------------------------
__global__ __launch_bounds__(256,4) void bwd_edge_k(
    const float* __restrict__ wS, const float* __restrict__ CS,
    const int* __restrict__ rowS, const int* __restrict__ colS, int E,
    const __bf16* __restrict__ W1t, const float* __restrict__ b1,
    const __bf16* __restrict__ W2t, const float* __restrict__ b2,
    const __bf16* __restrict__ W2c, const __bf16* __restrict__ W1c,
    const float* __restrict__ dagg, const float* __restrict__ xh,
    float* __restrict__ dxh, float* __restrict__ dC, float* __restrict__ dw,
    int accum)
{
  __shared__ __align__(16) __bf16 tb[64][136];     // 17.4 KB
  __shared__ float accL[32][128];                  // 16 KB
  __shared__ float wrow[64], Ce[64];
  __shared__ int gi[64], ci64[64], slotA[64], segKey[64];
  __shared__ int ndS;
  const int t = threadIdx.x;
  const int e0 = blockIdx.x*64;

  if (t < 64){
    int j = e0 + t;
    bool ok = j < E;
    int jc = ok ? j : E-1;
    wrow[t] = wS[jc];
    Ce[t]   = ok ? CS[jc] : 0.f;
    int key = rowS[jc];       // sorted: gather xh / scatter dxh
    ci64[t] = colS[jc];       // gather dagg
    gi[t]   = key;
    int kp = __shfl_up(key, 1);
    int flag = (t>0 && key != kp) ? 1 : 0;
    unsigned long long mask = __ballot(flag);
    int sl = (int)__popcll(mask & ((2ull<<t)-1ull));
    slotA[t] = sl;
    if ((flag || t==0) && sl < 32) segKey[sl] = key;
    if (t==63) ndS = sl+1;
  }
  #pragma unroll
  for (int p=t; p<32*128; p+=256) ((float*)accL)[p] = 0.f;
  __syncthreads();

  const int wid = t>>6, lane = t&63, quad = lane>>4, ln = lane&15;
  f32x4 acc[8];
  float sig[8][4];
  #pragma unroll
  for (int nt=0;nt<8;nt++) acc[nt] = (f32x4){0.f,0.f,0.f,0.f};

  // ---- GEMM1: t1 = ea @ W1 ; keep sig(t1), store ssp(t1) ----
  const float wa = wrow[wid*16 + ln];
  #pragma unroll
  for (int ks=0; ks<64; ks+=32){
    bf16x8 a;
    #pragma unroll
    for (int j=0;j<8;j++){
      int k = ks + quad*8 + j;
      float d = wa - (float)k*DMU;
      a[j] = (k<50) ? (__bf16)__expf(GC*d*d) : (__bf16)0.f;
    }
    #pragma unroll
    for (int nt=0; nt<8; nt++){
      bf16x8 b = *(const bf16x8*)(W1t + (size_t)(nt*16+ln)*64 + ks + quad*8);
      acc[nt] = __builtin_amdgcn_mfma_f32_16x16x32_bf16(a, b, acc[nt], 0, 0, 0);
    }
  }
  #pragma unroll
  for (int nt=0; nt<8; nt++){
    int c = nt*16 + ln;
    float bb = b1[c];
    #pragma unroll
    for (int reg=0; reg<4; reg++){
      int r = wid*16 + quad*4 + reg;
      float t1 = acc[nt][reg] + bb;
      sig[nt][reg] = sigf(t1);
      tb[r][c] = (__bf16)sspf(t1);
    }
  }
  __syncthreads();

  // ---- GEMM2: Wf = s1 @ W2 ----
  #pragma unroll
  for (int nt=0;nt<8;nt++) acc[nt] = (f32x4){0.f,0.f,0.f,0.f};
  #pragma unroll
  for (int ks=0; ks<128; ks+=32){
    bf16x8 a = *(const bf16x8*)&tb[wid*16 + ln][ks + quad*8];
    #pragma unroll
    for (int nt=0; nt<8; nt++){
      bf16x8 b = *(const bf16x8*)(W2t + (size_t)(nt*16+ln)*128 + ks + quad*8);
      acc[nt] = __builtin_amdgcn_mfma_f32_16x16x32_bf16(a, b, acc[nt], 0, 0, 0);
    }
  }
  __syncthreads();   // reads of tb (s1) done

  // ---- edge step: dC (sorted write), dxh -> LDS accum, dWf -> tb ----
  #pragma unroll
  for (int reg=0; reg<4; reg++){
    int r = wid*16 + quad*4 + reg;
    int j = e0 + r;
    float dcp = 0.f;
    if (j < E){
      float ce = Ce[r];
      size_t ri = (size_t)gi[r]*128;
      size_t cc = (size_t)ci64[r]*128;
      int sl = slotA[r];
      if (sl < 32){
        #pragma unroll
        for (int nt=0; nt<8; nt++){
          int c = nt*16 + ln;
          float wf = acc[nt][reg] + b2[c];
          float da = dagg[cc + c];
          float xv = xh[ri + c];
          dcp += da*xv*wf;
          atomicAdd(&accL[sl][c], da*ce*wf);
          tb[r][c] = (__bf16)(da*xv*ce);
        }
      } else {
        #pragma unroll
        for (int nt=0; nt<8; nt++){
          int c = nt*16 + ln;
          float wf = acc[nt][reg] + b2[c];
          float da = dagg[cc + c];
          float xv = xh[ri + c];
          dcp += da*xv*wf;
          atomicAdd(&dxh[ri + c], da*ce*wf);
          tb[r][c] = (__bf16)(da*xv*ce);
        }
      }
    } else {
      #pragma unroll
      for (int nt=0; nt<8; nt++) tb[r][nt*16+ln] = (__bf16)0.f;
    }
    dcp += __shfl_xor(dcp, 1);
    dcp += __shfl_xor(dcp, 2);
    dcp += __shfl_xor(dcp, 4);
    dcp += __shfl_xor(dcp, 8);
    if (ln==0 && j < E) dC[j] = accum ? (dC[j]+dcp) : dcp;
  }
  __syncthreads();

  // flush dxh LDS accumulator
  {
    int nd = ndS; if (nd > 32) nd = 32;
    for (int p=t; p<nd*128; p+=256){
      int sl = p>>7, c = p&127;
      atomicAdd(&dxh[(size_t)segKey[sl]*128 + c], accL[sl][c]);
    }
  }

  // ---- GEMM3: dt1 = (dWf @ W2^T) * sig ----
  #pragma unroll
  for (int nt=0;nt<8;nt++) acc[nt] = (f32x4){0.f,0.f,0.f,0.f};
  #pragma unroll
  for (int ks=0; ks<128; ks+=32){
    bf16x8 a = *(const bf16x8*)&tb[wid*16 + ln][ks + quad*8];
    #pragma unroll
    for (int nt=0; nt<8; nt++){
      bf16x8 b = *(const bf16x8*)(W2c + (size_t)(nt*16+ln)*128 + ks + quad*8);
      acc[nt] = __builtin_amdgcn_mfma_f32_16x16x32_bf16(a, b, acc[nt], 0, 0, 0);
    }
  }
  __syncthreads();   // reads of tb (dWf) done
  #pragma unroll
  for (int nt=0; nt<8; nt++){
    int c = nt*16 + ln;
    #pragma unroll
    for (int reg=0; reg<4; reg++){
      int r = wid*16 + quad*4 + reg;
      tb[r][c] = (__bf16)(acc[nt][reg] * sig[nt][reg]);
    }
  }
  __syncthreads();

  // ---- GEMM4: dea = dt1 @ W1^T ; contract to dw (sorted write) ----
  #pragma unroll
  for (int nt=0;nt<4;nt++) acc[nt] = (f32x4){0.f,0.f,0.f,0.f};
  #pragma unroll
  for (int ks=0; ks<128; ks+=32){
    bf16x8 a = *(const bf16x8*)&tb[wid*16 + ln][ks + quad*8];
    #pragma unroll
    for (int nt=0; nt<4; nt++){
      bf16x8 b = *(const bf16x8*)(W1c + (size_t)(nt*16+ln)*128 + ks + quad*8);
      acc[nt] = __builtin_amdgcn_mfma_f32_16x16x32_bf16(a, b, acc[nt], 0, 0, 0);
    }
  }
  #pragma unroll
  for (int reg=0; reg<4; reg++){
    int r = wid*16 + quad*4 + reg;
    int j = e0 + r;
    float w = wrow[r];
    float s = 0.f;
    #pragma unroll
    for (int nt=0; nt<4; nt++){
      int c = nt*16 + ln;
      if (c < 50){
        float d = w - (float)c*DMU;
        s += acc[nt][reg] * (2.f*GC*d) * __expf(GC*d*d);
      }
    }
    s += __shfl_xor(s, 1);
    s += __shfl_xor(s, 2);
    s += __shfl_xor(s, 4);
    s += __shfl_xor(s, 8);
    if (ln==0 && j < E) dw[j] = accum ? (dw[j]+s) : s;
  }
}

// ---------------------------------------------------------------------------
// one-time bf16 weight conversion
// ---------------------------------------------------------------------------
__global__ void convw_k(const float* __restrict__ w1, const float* __restrict__ w2,
                        __bf16* __restrict__ W1t, __bf16* __restrict__ W2t,
                        __bf16* __restrict__ W2c, __bf16* __restrict__ W1c, int total)
{
  int idx = blockIdx.x*256 + threadIdx.x;
  if (idx >= total) return;
  int l = idx / 49152;
  int r = idx % 49152;
  if (r < 8192){                       // W1t[n][k] = w1[k][n], k<50
    int n = r / 64, k = r % 64;
    float v = (k<50) ? w1[(size_t)l*6400 + k*128 + n] : 0.f;
    W1t[(size_t)l*8192 + r] = (__bf16)v;
  } else if (r < 24576){               // W2t[n][k] = w2[k][n]
    int r2 = r - 8192;
    int n = r2 / 128, k = r2 % 128;
    W2t[(size_t)l*16384 + r2] = (__bf16)w2[(size_t)l*16384 + k*128 + n];
  } else if (r < 40960){               // W2c = w2 (elementwise)
    int r2 = r - 24576;
    W2c[(size_t)l*16384 + r2] = (__bf16)w2[(size_t)l*16384 + r2];
  } else {                             // W1c[n][k] = w1[n][k], n<50
    int r2 = r - 40960;
    int n = r2 / 128, k = r2 % 128;
    float v = (n<50) ? w1[(size_t)l*6400 + n*128 + k] : 0.f;
    W1c[(size_t)l*8192 + r2] = (__bf16)v;
  }
}

// ---------------------------------------------------------------------------
__global__ void edge_geom_k(const float* __restrict__ pos, const int* __restrict__ ei,
                            const float* __restrict__ off, const float* __restrict__ cell,
                            float* __restrict__ wv, float* __restrict__ Cv, int E)
{
  int e = blockIdx.x*256 + threadIdx.x;
  if (e>=E) return;
  int r = ei[e], c = ei[E+e];
  float o0=off[3*e], o1=off[3*e+1], o2=off[3*e+2];
  float d0 = o0*cell[0] + o1*cell[3] + o2*cell[6];
  float d1 = o0*cell[1] + o1*cell[4] + o2*cell[7];
  float d2 = o0*cell[2] + o1*cell[5] + o2*cell[8];
  float v0 = pos[3*r+0]-pos[3*c+0]+d0;
  float v1 = pos[3*r+1]-pos[3*c+1]+d1;
  float v2 = pos[3*r+2]-pos[3*c+2]+d2;
  float w = sqrtf(v0*v0+v1*v1+v2*v2);
  wv[e]=w;
  Cv[e]=0.5f*cosf(w*(PI_F/4.0f)) + 0.5f;
}

__global__ void embed_k(const float* __restrict__ emb, const int* __restrict__ z,
                        float* __restrict__ h, int total){
  int i = blockIdx.x*256 + threadIdx.x;
  if (i < total){ int n=i>>7, j=i&127; h[i] = emb[(size_t)z[n]*128 + j]; }
}

// readout energy
__global__ void head_k(const float* __restrict__ u, const float* __restrict__ o2,
                       const float* __restrict__ o2b, float* __restrict__ out0, int N){
  int n = blockIdx.x*256 + threadIdx.x;
  float s = 0.f;
  if (n < N){
    #pragma unroll
    for (int k=0;k<64;k+=4){
      float4 uv = *(const float4*)(u + (size_t)n*64 + k);
      float4 ov = *(const float4*)(o2 + k);
      s += sspf(uv.x)*ov.x + sspf(uv.y)*ov.y + sspf(uv.z)*ov.z + sspf(uv.w)*ov.w;
    }
  }
  #pragma unroll
  for (int m=1;m<64;m<<=1) s += __shfl_xor(s, m);
  __shared__ float red[4];
  int lane = threadIdx.x&63, w = threadIdx.x>>6;
  if (lane==0) red[w]=s;
  __syncthreads();
  if (threadIdx.x==0){
    float tot = red[0]+red[1]+red[2]+red[3];
    if (blockIdx.x==0) tot += (float)N * o2b[0];
    atomicAdd(out0, tot);
  }
}

// forces in sorted-j space: all per-edge arrays coalesced; pos gathers row-clustered
__global__ void force_k(const float* __restrict__ dwS, const float* __restrict__ dCS,
                        const float* __restrict__ wSv, const int* __restrict__ rowS,
                        const int* __restrict__ colS, const float* __restrict__ offS,
                        const float* __restrict__ pos, const float* __restrict__ cell,
                        float* __restrict__ f, int E)
{
  int j = blockIdx.x*256 + threadIdx.x;
  if (j>=E) return;
  int r = rowS[j], c = colS[j];
  float o0=offS[3*j], o1=offS[3*j+1], o2=offS[3*j+2];
  float d0 = o0*cell[0] + o1*cell[3] + o2*cell[6];
  float d1 = o0*cell[1] + o1*cell[4] + o2*cell[7];
  float d2 = o0*cell[2] + o1*cell[5] + o2*cell[8];
  float v0 = pos[3*r+0]-pos[3*c+0]+d0;
  float v1 = pos[3*r+1]-pos[3*c+1]+d1;
  float v2 = pos[3*r+2]-pos[3*c+2]+d2;
  float w = wSv[j];
  float dwt = dwS[j] + dCS[j] * (-0.5f*(PI_F/4.0f)) * __sinf(w*(PI_F/4.0f));
  float s = dwt / w;
  atomicAdd(&f[3*r+0], -v0*s); atomicAdd(&f[3*r+1], -v1*s); atomicAdd(&f[3*r+2], -v2*s);
  atomicAdd(&f[3*c+0],  v0*s); atomicAdd(&f[3*c+1],  v1*s); atomicAdd(&f[3*c+2],  v2*s);
}

// ---------------------------------------------------------------------------
extern "C" void kernel_launch(void* const* d_in, const int* in_sizes, int n_in,
                              void* d_out, int out_size, void* d_ws, size_t ws_size,
                              hipStream_t stream)
{
  const int N = in_sizes[0];
  const int E = in_sizes[2]/2;
  const int L = 6;
  const int* z        = (const int*)d_in[0];
  const float* pos    = (const float*)d_in[1];
  const int* ei       = (const int*)d_in[2];
  const float* offset = (const float*)d_in[3];
  const float* cell   = (const float*)d_in[4];
  const float* emb    = (const float*)d_in[5];
  const float* mlp_w1 = (const float*)d_in[6];
  const float* mlp_b1 = (const float*)d_in[7];
  const float* mlp_w2 = (const float*)d_in[8];
  const float* mlp_b2 = (const float*)d_in[9];
  const float* conv_w1= (const float*)d_in[10];
  const float* conv_w2= (const float*)d_in[11];
  const float* conv_b2= (const float*)d_in[12];
  const float* lin_w  = (const float*)d_in[13];
  const float* lin_b  = (const float*)d_in[14];
  const float* out1_w = (const float*)d_in[15];
  const float* out1_b = (const float*)d_in[16];
  const float* out2_w = (const float*)d_in[17];
  const float* out2_b = (const float*)d_in[18];
  float* out = (float*)d_out;

  char* wp = (char*)d_ws;
  auto alloc = [&](size_t bytes)->char*{ char* p = wp; wp += (bytes + 255) & ~(size_t)255; return p; };
  float* wbuf = (float*)alloc((size_t)E*4);
  float* Cbuf = (float*)alloc((size_t)E*4);
  float* dCb  = (float*)alloc((size_t)E*4);   // row-sorted coords
  float* dwb  = (float*)alloc((size_t)E*4);   // row-sorted coords
  float* xh   = (float*)alloc((size_t)L*N*128*4);
  float* mbuf = (float*)alloc((size_t)L*N*128*4);
  float* ubuf = (float*)alloc((size_t)N*64*4);
  float* hbuf = (float*)alloc((size_t)N*128*4);
  float* Gbuf = (float*)alloc((size_t)N*128*4);
  float* bufA = (float*)alloc((size_t)N*128*4);
  float* bufB = (float*)alloc((size_t)N*128*4);
  float* bufC = (float*)alloc((size_t)N*128*4);   // dxh
  float* aggb = (float*)alloc((size_t)N*128*4);
  __bf16* W1t = (__bf16*)alloc((size_t)L*8192*2);
  __bf16* W2t = (__bf16*)alloc((size_t)L*16384*2);
  __bf16* W2c = (__bf16*)alloc((size_t)L*16384*2);
  __bf16* W1c = (__bf16*)alloc((size_t)L*8192*2);
  // counting-sort + sorted metadata
  int* histb    = (int*)alloc((size_t)N*4);
  int* scanb    = (int*)alloc((size_t)(N+1)*4);
  int* colidx   = (int*)alloc((size_t)E*4);
  int* rowidx   = (int*)alloc((size_t)E*4);
  int* cursor   = (int*)alloc((size_t)N*4);
  int*   rowR = (int*)alloc((size_t)E*4);
  int*   colR = (int*)alloc((size_t)E*4);
  float* wR   = (float*)alloc((size_t)E*4);
  float* CR   = (float*)alloc((size_t)E*4);
  float* offR = (float*)alloc((size_t)E*12);
  int*   rowC = (int*)alloc((size_t)E*4);
  int*   colC = (int*)alloc((size_t)E*4);
  float* wC   = (float*)alloc((size_t)E*4);
  float* CC   = (float*)alloc((size_t)E*4);

  const int egrid = (E+255)/256;
  const int eg64 = (E+63)/64;
  const int ng = (N+127)/128;
  const int wtotal = L*49152;

  hipMemsetAsync(d_out, 0, (size_t)out_size*4, stream);
  convw_k<<<(wtotal+255)/256,256,0,stream>>>(mlp_w1, mlp_w2, W1t, W2t, W2c, W1c, wtotal);
  edge_geom_k<<<egrid,256,0,stream>>>(pos, ei, offset, cell, wbuf, Cbuf, E);
  embed_k<<<(N*128+255)/256,256,0,stream>>>(emb, z, hbuf, N*128);

  // counting sorts + metadata reorder
  hipMemsetAsync(histb, 0, (size_t)N*4, stream);
  hist_k<<<egrid,256,0,stream>>>(ei+E, histb, E);
  scan_k<<<1,1024,0,stream>>>(histb, scanb, N);
  hipMemcpyAsync(cursor, scanb, (size_t)N*4, hipMemcpyDeviceToDevice, stream);
  scatter_k<<<egrid,256,0,stream>>>(ei+E, cursor, colidx, E);
  hipMemsetAsync(histb, 0, (size_t)N*4, stream);
  hist_k<<<egrid,256,0,stream>>>(ei, histb, E);
  scan_k<<<1,1024,0,stream>>>(histb, scanb, N);
  hipMemcpyAsync(cursor, scanb, (size_t)N*4, hipMemcpyDeviceToDevice, stream);
  scatter_k<<<egrid,256,0,stream>>>(ei, cursor, rowidx, E);
  reorder_k<<<egrid,256,0,stream>>>(rowidx, ei, wbuf, Cbuf, offset, E, rowR, colR, wR, CR, offR);
  reorder_k<<<egrid,256,0,stream>>>(colidx, ei, wbuf, Cbuf, nullptr, E, rowC, colC, wC, CC, nullptr);

  // ---------------- forward ----------------
  for (int i=0;i<L;i++){
    const float* b1i = mlp_b1 + (size_t)i*128;
    const float* b2i = mlp_b2 + (size_t)i*128;
    const float* cw1i= conv_w1+ (size_t)i*128*128;
    const float* cw2i= conv_w2+ (size_t)i*128*128;
    const float* cb2i= conv_b2+ (size_t)i*128;
    const float* lwi = lin_w  + (size_t)i*128*128;
    const float* lbi = lin_b  + (size_t)i*128;
    float* xhi = xh   + (size_t)i*N*128;
    float* mi  = mbuf + (size_t)i*N*128;

    gemm_k<128,128,false,0,false,0,false><<<ng,256,0,stream>>>(
      hbuf, 128, nullptr, nullptr, cw1i, 128, 128, nullptr, nullptr, nullptr, xhi, N);
    hipMemsetAsync(aggb, 0, (size_t)N*128*4, stream);
    fwd_edge_k<<<eg64,256,0,stream>>>(
      wC, CC, rowC, colC, E, W1t + (size_t)i*8192, b1i, W2t + (size_t)i*16384, b2i, xhi, aggb);
    gemm_k<128,128,false,0,true,0,false><<<ng,256,0,stream>>>(
      aggb, 128, nullptr, nullptr, cw2i, 128, 128, cb2i, nullptr, nullptr, mi, N);
    gemm_k<128,128,false,1,true,0,true><<<ng,256,0,stream>>>(
      mi, 128, nullptr, nullptr, lwi, 128, 128, lbi, hbuf, nullptr, hbuf, N);
  }

  // head: u = h@o1+b ; E = sum ssp(u)@o2 + N*o2b ; G = (o2*sig(u))@o1^T
  gemm_k<128,64,false,0,true,0,false><<<ng,256,0,stream>>>(
    hbuf, 128, nullptr, nullptr, out1_w, 128, 64, out1_b, nullptr, nullptr, ubuf, N);
  head_k<<<(N+255)/256,256,0,stream>>>(ubuf, out2_w, out2_b, out, N);
  gemm_k<64,128,true,3,false,0,false><<<ng,256,0,stream>>>(
    ubuf, 64, nullptr, out2_w, out1_w, 64, 128, nullptr, nullptr, nullptr, Gbuf, N);

  // ---------------- backward ----------------
  for (int i=L-1;i>=0;i--){
    const float* b1i = mlp_b1 + (size_t)i*128;
    const float* b2i = mlp_b2 + (size_t)i*128;
    const float* cw1i= conv_w1+ (size_t)i*128*128;
    const float* cw2i= conv_w2+ (size_t)i*128*128;
    const float* lwi = lin_w  + (size_t)i*128*128;
    float* xhi = xh   + (size_t)i*N*128;
    float* mi  = mbuf + (size_t)i*N*128;
    int first = (i==L-1) ? 0 : 1;

    gemm_k<128,128,true,0,false,0,false><<<ng,256,0,stream>>>(
      Gbuf, 128, nullptr, nullptr, lwi, 128, 128, nullptr, nullptr, nullptr, bufA, N);
    gemm_k<128,128,true,2,false,0,false><<<ng,256,0,stream>>>(
      bufA, 128, mi, nullptr, cw2i, 128, 128, nullptr, nullptr, nullptr, bufB, N);
    hipMemsetAsync(bufC, 0, (size_t)N*128*4, stream);
    bwd_edge_k<<<eg64,256,0,stream>>>(
      wR, CR, rowR, colR, E,
      W1t + (size_t)i*8192, b1i, W2t + (size_t)i*16384, b2i,
      W2c + (size_t)i*16384, W1c + (size_t)i*8192,
      bufB, xhi, bufC, dCb, dwb, first);
    gemm_k<128,128,true,0,false,0,true><<<ng,256,0,stream>>>(
      bufC, 128, nullptr, nullptr, cw1i, 128, 128, nullptr, Gbuf, nullptr, Gbuf, N);
  }

  force_k<<<egrid,256,0,stream>>>(dwb, dCb, wR, rowR, colR, offR, pos, cell, out+1, E);
}

// Round 9
// 4159.285 us; speedup vs baseline: 1.3369x; 1.2884x over previous
//
#include <hip/hip_runtime.h>
#include <math.h>

#define LN2F 0.69314718055994530942f
#define PI_F 3.14159265358979323846f
constexpr float DMU = 4.0f/49.0f;          // gaussian spacing, linspace(0,4,50)
constexpr float GC  = -0.5f/(DMU*DMU);     // smearing coeff

typedef __bf16 bf16x8 __attribute__((ext_vector_type(8)));
typedef float  f32x4  __attribute__((ext_vector_type(4)));

// fast-math: v_exp_f32 / v_log_f32 / v_rcp_f32
__device__ __forceinline__ float sspf(float x){
  return fmaxf(x, 0.f) + __logf(1.f + __expf(-fabsf(x))) - LN2F;
}
__device__ __forceinline__ float sigf(float x){
  return __builtin_amdgcn_rcpf(1.f + __expf(-x));
}

// ---------------------------------------------------------------------------
// fp32 GEMM (node-level): out[M,NN] = epi( A'[M,KK] @ B[KK,NN] )
// ---------------------------------------------------------------------------
template<int KK,int NN,bool TRB,int ATR,bool BIAS,int OTR,bool RES>
__global__ __launch_bounds__(256) void gemm_k(
    const float* __restrict__ A, int lda,
    const float* __restrict__ aux, const float* __restrict__ auxvec,
    const float* __restrict__ B, int Kreal, int Nreal,
    const float* __restrict__ bias, const float* __restrict__ res,
    const float* __restrict__ oaux, float* __restrict__ out, int M)
{
  constexpr int TM = 128, BK = 32;
  constexpr int TX = (NN==128)?16:8;
  constexpr int RT = (NN==128)?8:4;
  __shared__ float As[BK][TM+4];
  __shared__ float Bs[BK][NN+4];
  const int t = threadIdx.x;
  const int tx = t % TX, ty = t / TX;
  const int m0 = blockIdx.x * TM;
  float acc[RT][8];
  #pragma unroll
  for (int i=0;i<RT;i++)
    #pragma unroll
    for (int j=0;j<8;j++) acc[i][j]=0.f;

  for (int kc=0; kc<KK; kc+=BK){
    #pragma unroll
    for (int j=0;j<4;j++){
      int p = t + j*256;
      int m = p >> 3;
      int kv = (p & 7) << 2;
      float4 v = make_float4(0.f,0.f,0.f,0.f);
      if (m0+m < M){
        v = *(const float4*)(A + (size_t)(m0+m)*lda + kc + kv);
        if constexpr (ATR==1){ v.x=sspf(v.x); v.y=sspf(v.y); v.z=sspf(v.z); v.w=sspf(v.w); }
        else if constexpr (ATR==2){
          float4 av = *(const float4*)(aux + (size_t)(m0+m)*lda + kc + kv);
          v.x*=sigf(av.x); v.y*=sigf(av.y); v.z*=sigf(av.z); v.w*=sigf(av.w);
        }
        else if constexpr (ATR==3){
          int kg = kc+kv;
          v.x = auxvec[kg+0]*sigf(v.x); v.y = auxvec[kg+1]*sigf(v.y);
          v.z = auxvec[kg+2]*sigf(v.z); v.w = auxvec[kg+3]*sigf(v.w);
        }
      }
      As[kv+0][m]=v.x; As[kv+1][m]=v.y; As[kv+2][m]=v.z; As[kv+3][m]=v.w;
    }
    if constexpr (!TRB){
      #pragma unroll
      for (int j=0;j<(BK*NN)/1024;j++){
        int p = t + j*256;
        int k = p / (NN/4);
        int nv = (p % (NN/4)) << 2;
        float4 v = make_float4(0.f,0.f,0.f,0.f);
        if (kc + k < Kreal) v = *(const float4*)(B + (size_t)(kc+k)*NN + nv);
        *(float4*)&Bs[k][nv] = v;
      }
    } else {
      #pragma unroll
      for (int j=0;j<(BK*NN)/1024;j++){
        int p = t + j*256;
        int n = p >> 3;
        int kv = (p & 7) << 2;
        float4 v = make_float4(0.f,0.f,0.f,0.f);
        if (n < Nreal) v = *(const float4*)(B + (size_t)n*KK + kc + kv);
        Bs[kv+0][n]=v.x; Bs[kv+1][n]=v.y; Bs[kv+2][n]=v.z; Bs[kv+3][n]=v.w;
      }
    }
    __syncthreads();
    #pragma unroll
    for (int k=0;k<BK;k++){
      float a[RT], b[8];
      #pragma unroll
      for (int i=0;i<RT;i+=4) *(float4*)&a[i] = *(const float4*)&As[k][ty*RT+i];
      *(float4*)&b[0] = *(const float4*)&Bs[k][tx*8];
      *(float4*)&b[4] = *(const float4*)&Bs[k][tx*8+4];
      #pragma unroll
      for (int i=0;i<RT;i++)
        #pragma unroll
        for (int j=0;j<8;j++)
          acc[i][j] = fmaf(a[i], b[j], acc[i][j]);
    }
    __syncthreads();
  }
  #pragma unroll
  for (int i=0;i<RT;i++){
    int r = m0 + ty*RT + i;
    if (r < M){
      float vo[8];
      #pragma unroll
      for (int j=0;j<8;j++){
        float v = acc[i][j];
        int c = tx*8 + j;
        if constexpr (BIAS) v += bias[c];
        if constexpr (OTR==1) v = sspf(v);
        else if constexpr (OTR==2) v *= sigf(oaux[(size_t)r*NN + c]);
        if constexpr (RES) v += res[(size_t)r*NN + c];
        vo[j] = v;
      }
      *(float4*)(out + (size_t)r*NN + tx*8)     = make_float4(vo[0],vo[1],vo[2],vo[3]);
      *(float4*)(out + (size_t)r*NN + tx*8 + 4) = make_float4(vo[4],vo[5],vo[6],vo[7]);
    }
  }
}

// ---------------------------------------------------------------------------
// Fused FORWARD edge kernel (round-5 structure: W2 staged in LDS):
//   ea(w) -> s1=ssp(ea@W1+b1) -> Wf=s1@W2+b2 -> agg[col] += xh[row]*Wf*C
// ---------------------------------------------------------------------------
__global__ __launch_bounds__(256) void fwd_edge_k(
    const float* __restrict__ wv, const float* __restrict__ Cv,
    const int* __restrict__ ei, int E,
    const __bf16* __restrict__ W1t, const float* __restrict__ b1,
    const __bf16* __restrict__ W2t, const float* __restrict__ b2,
    const float* __restrict__ xh, float* __restrict__ agg)
{
  __shared__ __align__(16) __bf16 W2s[128][136];   // 34.8 KB
  __shared__ __align__(16) __bf16 s1t[64][136];    // 17.4 KB
  __shared__ float wrow[64], Ce[64];
  __shared__ int rowi[64], coli[64];
  const int t = threadIdx.x;
  const int e0 = blockIdx.x*64;

  #pragma unroll
  for (int it=0; it<8; ++it){
    int p = t + it*256;
    int row = p >> 4;
    int ko = (p & 15)*8;
    *(uint4*)&W2s[row][ko] = *(const uint4*)(W2t + (size_t)row*128 + ko);
  }
  if (t < 64){
    int e = e0 + t;
    bool ok = e < E;
    wrow[t] = ok ? wv[e] : 0.f;
    Ce[t]   = ok ? Cv[e] : 0.f;
    rowi[t] = ok ? ei[e] : 0;
    coli[t] = ok ? ei[E+e] : 0;
  }
  __syncthreads();

  const int wid = t>>6, lane = t&63, quad = lane>>4, ln = lane&15;
  f32x4 acc[8];
  #pragma unroll
  for (int nt=0;nt<8;nt++) acc[nt] = (f32x4){0.f,0.f,0.f,0.f};

  // ---- GEMM1: t1 = ea @ W1 ----
  const float wa = wrow[wid*16 + ln];
  #pragma unroll
  for (int ks=0; ks<64; ks+=32){
    bf16x8 a;
    #pragma unroll
    for (int j=0;j<8;j++){
      int k = ks + quad*8 + j;
      float d = wa - (float)k*DMU;
      a[j] = (k<50) ? (__bf16)__expf(GC*d*d) : (__bf16)0.f;
    }
    #pragma unroll
    for (int nt=0; nt<8; nt++){
      bf16x8 b = *(const bf16x8*)(W1t + (size_t)(nt*16+ln)*64 + ks + quad*8);
      acc[nt] = __builtin_amdgcn_mfma_f32_16x16x32_bf16(a, b, acc[nt], 0, 0, 0);
    }
  }
  // s1 = ssp(t1+b1) -> LDS transpose
  #pragma unroll
  for (int nt=0; nt<8; nt++){
    int c = nt*16 + ln;
    float bb = b1[c];
    #pragma unroll
    for (int reg=0; reg<4; reg++){
      int r = wid*16 + quad*4 + reg;
      s1t[r][c] = (__bf16)sspf(acc[nt][reg] + bb);
    }
  }
  __syncthreads();

  // ---- GEMM2: Wf = s1 @ W2 (LDS) ----
  #pragma unroll
  for (int nt=0;nt<8;nt++) acc[nt] = (f32x4){0.f,0.f,0.f,0.f};
  #pragma unroll
  for (int ks=0; ks<128; ks+=32){
    bf16x8 a = *(const bf16x8*)&s1t[wid*16 + ln][ks + quad*8];
    #pragma unroll
    for (int nt=0; nt<8; nt++){
      bf16x8 b = *(const bf16x8*)&W2s[nt*16 + ln][ks + quad*8];
      acc[nt] = __builtin_amdgcn_mfma_f32_16x16x32_bf16(a, b, acc[nt], 0, 0, 0);
    }
  }

  // ---- scatter: agg[col] += xh[row]*(Wf+b2)*C ----
  #pragma unroll
  for (int reg=0; reg<4; reg++){
    int r = wid*16 + quad*4 + reg;
    int e = e0 + r;
    if (e < E){
      float ce = Ce[r];
      size_t ri = (size_t)rowi[r]*128;
      size_t ci = (size_t)coli[r]*128;
      #pragma unroll
      for (int nt=0; nt<8; nt++){
        int c = nt*16 + ln;
        float wf = acc[nt][reg] + b2[c];
        atomicAdd(&agg[ci + c], xh[ri + c]*ce*wf);
      }
    }
  }
}

// ---------------------------------------------------------------------------
// Fused BACKWARD edge kernel (round-6 structure: weights from global, 18KB LDS)
// ---------------------------------------------------------------------------
__global__ __launch_bounds__(256,4) void bwd_edge_k(
    const float* __restrict__ wv, const float* __restrict__ Cv,
    const int* __restrict__ ei, int E,
    const __bf16* __restrict__ W1t, const float* __restrict__ b1,
    const __bf16* __restrict__ W2t, const float* __restrict__ b2,
    const __bf16* __restrict__ W2c, const __bf16* __restrict__ W1c,
    const float* __restrict__ dagg, const float* __restrict__ xh,
    float* __restrict__ dxh, float* __restrict__ dC, float* __restrict__ dw,
    int accum)
{
  __shared__ __align__(16) __bf16 tb[64][136];     // 17.4 KB
  __shared__ float wrow[64], Ce[64];
  __shared__ int rowi[64], coli[64];
  const int t = threadIdx.x;
  const int e0 = blockIdx.x*64;

  if (t < 64){
    int e = e0 + t;
    bool ok = e < E;
    wrow[t] = ok ? wv[e] : 0.f;
    Ce[t]   = ok ? Cv[e] : 0.f;
    rowi[t] = ok ? ei[e] : 0;
    coli[t] = ok ? ei[E+e] : 0;
  }
  __syncthreads();

  const int wid = t>>6, lane = t&63, quad = lane>>4, ln = lane&15;
  f32x4 acc[8];
  float sig[8][4];
  #pragma unroll
  for (int nt=0;nt<8;nt++) acc[nt] = (f32x4){0.f,0.f,0.f,0.f};

  // ---- GEMM1: t1 = ea @ W1 ; keep sig(t1), store ssp(t1) ----
  const float wa = wrow[wid*16 + ln];
  #pragma unroll
  for (int ks=0; ks<64; ks+=32){
    bf16x8 a;
    #pragma unroll
    for (int j=0;j<8;j++){
      int k = ks + quad*8 + j;
      float d = wa - (float)k*DMU;
      a[j] = (k<50) ? (__bf16)__expf(GC*d*d) : (__bf16)0.f;
    }
    #pragma unroll
    for (int nt=0; nt<8; nt++){
      bf16x8 b = *(const bf16x8*)(W1t + (size_t)(nt*16+ln)*64 + ks + quad*8);
      acc[nt] = __builtin_amdgcn_mfma_f32_16x16x32_bf16(a, b, acc[nt], 0, 0, 0);
    }
  }
  #pragma unroll
  for (int nt=0; nt<8; nt++){
    int c = nt*16 + ln;
    float bb = b1[c];
    #pragma unroll
    for (int reg=0; reg<4; reg++){
      int r = wid*16 + quad*4 + reg;
      float t1 = acc[nt][reg] + bb;
      sig[nt][reg] = sigf(t1);
      tb[r][c] = (__bf16)sspf(t1);
    }
  }
  __syncthreads();

  // ---- GEMM2: Wf = s1 @ W2 (B from global) ----
  #pragma unroll
  for (int nt=0;nt<8;nt++) acc[nt] = (f32x4){0.f,0.f,0.f,0.f};
  #pragma unroll
  for (int ks=0; ks<128; ks+=32){
    bf16x8 a = *(const bf16x8*)&tb[wid*16 + ln][ks + quad*8];
    #pragma unroll
    for (int nt=0; nt<8; nt++){
      bf16x8 b = *(const bf16x8*)(W2t + (size_t)(nt*16+ln)*128 + ks + quad*8);
      acc[nt] = __builtin_amdgcn_mfma_f32_16x16x32_bf16(a, b, acc[nt], 0, 0, 0);
    }
  }
  __syncthreads();   // reads of tb (s1) done

  // ---- edge step: dC, dxh scatter, dWf -> tb ----
  #pragma unroll
  for (int reg=0; reg<4; reg++){
    int r = wid*16 + quad*4 + reg;
    int e = e0 + r;
    float dcp = 0.f;
    if (e < E){
      float ce = Ce[r];
      size_t ri = (size_t)rowi[r]*128;
      size_t ci = (size_t)coli[r]*128;
      #pragma unroll
      for (int nt=0; nt<8; nt++){
        int c = nt*16 + ln;
        float wf = acc[nt][reg] + b2[c];
        float da = dagg[ci + c];
        float xv = xh[ri + c];
        dcp += da*xv*wf;
        atomicAdd(&dxh[ri + c], da*ce*wf);
        tb[r][c] = (__bf16)(da*xv*ce);
      }
    } else {
      #pragma unroll
      for (int nt=0; nt<8; nt++) tb[r][nt*16+ln] = (__bf16)0.f;
    }
    dcp += __shfl_xor(dcp, 1);
    dcp += __shfl_xor(dcp, 2);
    dcp += __shfl_xor(dcp, 4);
    dcp += __shfl_xor(dcp, 8);
    if (ln==0 && e < E) dC[e] = accum ? (dC[e]+dcp) : dcp;
  }
  __syncthreads();

  // ---- GEMM3: dt1 = (dWf @ W2^T) * sig (B from global W2c) ----
  #pragma unroll
  for (int nt=0;nt<8;nt++) acc[nt] = (f32x4){0.f,0.f,0.f,0.f};
  #pragma unroll
  for (int ks=0; ks<128; ks+=32){
    bf16x8 a = *(const bf16x8*)&tb[wid*16 + ln][ks + quad*8];
    #pragma unroll
    for (int nt=0; nt<8; nt++){
      bf16x8 b = *(const bf16x8*)(W2c + (size_t)(nt*16+ln)*128 + ks + quad*8);
      acc[nt] = __builtin_amdgcn_mfma_f32_16x16x32_bf16(a, b, acc[nt], 0, 0, 0);
    }
  }
  __syncthreads();   // reads of tb (dWf) done
  #pragma unroll
  for (int nt=0; nt<8; nt++){
    int c = nt*16 + ln;
    #pragma unroll
    for (int reg=0; reg<4; reg++){
      int r = wid*16 + quad*4 + reg;
      tb[r][c] = (__bf16)(acc[nt][reg] * sig[nt][reg]);
    }
  }
  __syncthreads();

  // ---- GEMM4: dea = dt1 @ W1^T ; contract to dw ----
  #pragma unroll
  for (int nt=0;nt<4;nt++) acc[nt] = (f32x4){0.f,0.f,0.f,0.f};
  #pragma unroll
  for (int ks=0; ks<128; ks+=32){
    bf16x8 a = *(const bf16x8*)&tb[wid*16 + ln][ks + quad*8];
    #pragma unroll
    for (int nt=0; nt<4; nt++){
      bf16x8 b = *(const bf16x8*)(W1c + (size_t)(nt*16+ln)*128 + ks + quad*8);
      acc[nt] = __builtin_amdgcn_mfma_f32_16x16x32_bf16(a, b, acc[nt], 0, 0, 0);
    }
  }
  #pragma unroll
  for (int reg=0; reg<4; reg++){
    int r = wid*16 + quad*4 + reg;
    int e = e0 + r;
    float w = wrow[r];
    float s = 0.f;
    #pragma unroll
    for (int nt=0; nt<4; nt++){
      int c = nt*16 + ln;
      if (c < 50){
        float d = w - (float)c*DMU;
        s += acc[nt][reg] * (2.f*GC*d) * __expf(GC*d*d);
      }
    }
    s += __shfl_xor(s, 1);
    s += __shfl_xor(s, 2);
    s += __shfl_xor(s, 4);
    s += __shfl_xor(s, 8);
    if (ln==0 && e < E) dw[e] = accum ? (dw[e]+s) : s;
  }
}

// ---------------------------------------------------------------------------
// one-time bf16 weight conversion
// ---------------------------------------------------------------------------
__global__ void convw_k(const float* __restrict__ w1, const float* __restrict__ w2,
                        __bf16* __restrict__ W1t, __bf16* __restrict__ W2t,
                        __bf16* __restrict__ W2c, __bf16* __restrict__ W1c, int total)
{
  int idx = blockIdx.x*256 + threadIdx.x;
  if (idx >= total) return;
  int l = idx / 49152;
  int r = idx % 49152;
  if (r < 8192){                       // W1t[n][k] = w1[k][n], k<50
    int n = r / 64, k = r % 64;
    float v = (k<50) ? w1[(size_t)l*6400 + k*128 + n] : 0.f;
    W1t[(size_t)l*8192 + r] = (__bf16)v;
  } else if (r < 24576){               // W2t[n][k] = w2[k][n]
    int r2 = r - 8192;
    int n = r2 / 128, k = r2 % 128;
    W2t[(size_t)l*16384 + r2] = (__bf16)w2[(size_t)l*16384 + k*128 + n];
  } else if (r < 40960){               // W2c = w2 (elementwise)
    int r2 = r - 24576;
    W2c[(size_t)l*16384 + r2] = (__bf16)w2[(size_t)l*16384 + r2];
  } else {                             // W1c[n][k] = w1[n][k], n<50
    int r2 = r - 40960;
    int n = r2 / 128, k = r2 % 128;
    float v = (n<50) ? w1[(size_t)l*6400 + n*128 + k] : 0.f;
    W1c[(size_t)l*8192 + r2] = (__bf16)v;
  }
}

// ---------------------------------------------------------------------------
__global__ void edge_geom_k(const float* __restrict__ pos, const int* __restrict__ ei,
                            const float* __restrict__ off, const float* __restrict__ cell,
                            float* __restrict__ wv, float* __restrict__ Cv, int E)
{
  int e = blockIdx.x*256 + threadIdx.x;
  if (e>=E) return;
  int r = ei[e], c = ei[E+e];
  float o0=off[3*e], o1=off[3*e+1], o2=off[3*e+2];
  float d0 = o0*cell[0] + o1*cell[3] + o2*cell[6];
  float d1 = o0*cell[1] + o1*cell[4] + o2*cell[7];
  float d2 = o0*cell[2] + o1*cell[5] + o2*cell[8];
  float v0 = pos[3*r+0]-pos[3*c+0]+d0;
  float v1 = pos[3*r+1]-pos[3*c+1]+d1;
  float v2 = pos[3*r+2]-pos[3*c+2]+d2;
  float w = sqrtf(v0*v0+v1*v1+v2*v2);
  wv[e]=w;
  Cv[e]=0.5f*cosf(w*(PI_F/4.0f)) + 0.5f;
}

__global__ void embed_k(const float* __restrict__ emb, const int* __restrict__ z,
                        float* __restrict__ h, int total){
  int i = blockIdx.x*256 + threadIdx.x;
  if (i < total){ int n=i>>7, j=i&127; h[i] = emb[(size_t)z[n]*128 + j]; }
}

// readout energy
__global__ void head_k(const float* __restrict__ u, const float* __restrict__ o2,
                       const float* __restrict__ o2b, float* __restrict__ out0, int N){
  int n = blockIdx.x*256 + threadIdx.x;
  float s = 0.f;
  if (n < N){
    #pragma unroll
    for (int k=0;k<64;k+=4){
      float4 uv = *(const float4*)(u + (size_t)n*64 + k);
      float4 ov = *(const float4*)(o2 + k);
      s += sspf(uv.x)*ov.x + sspf(uv.y)*ov.y + sspf(uv.z)*ov.z + sspf(uv.w)*ov.w;
    }
  }
  #pragma unroll
  for (int m=1;m<64;m<<=1) s += __shfl_xor(s, m);
  __shared__ float red[4];
  int lane = threadIdx.x&63, w = threadIdx.x>>6;
  if (lane==0) red[w]=s;
  __syncthreads();
  if (threadIdx.x==0){
    float tot = red[0]+red[1]+red[2]+red[3];
    if (blockIdx.x==0) tot += (float)N * o2b[0];
    atomicAdd(out0, tot);
  }
}

// forces: recompute vec, dvec = vec*(dw + dC*dCdw)/w, atomic scatter to f
__global__ void force_k(const float* __restrict__ dw, const float* __restrict__ dC,
                        const float* __restrict__ wv,
                        const float* __restrict__ pos, const int* __restrict__ ei,
                        const float* __restrict__ off, const float* __restrict__ cell,
                        float* __restrict__ f, int E)
{
  int e = blockIdx.x*256 + threadIdx.x;
  if (e>=E) return;
  int r = ei[e], c = ei[E+e];
  float o0=off[3*e], o1=off[3*e+1], o2=off[3*e+2];
  float d0 = o0*cell[0] + o1*cell[3] + o2*cell[6];
  float d1 = o0*cell[1] + o1*cell[4] + o2*cell[7];
  float d2 = o0*cell[2] + o1*cell[5] + o2*cell[8];
  float v0 = pos[3*r+0]-pos[3*c+0]+d0;
  float v1 = pos[3*r+1]-pos[3*c+1]+d1;
  float v2 = pos[3*r+2]-pos[3*c+2]+d2;
  float w = wv[e];
  float dwt = dw[e] + dC[e] * (-0.5f*(PI_F/4.0f)) * __sinf(w*(PI_F/4.0f));
  float s = dwt / w;
  atomicAdd(&f[3*r+0], -v0*s); atomicAdd(&f[3*r+1], -v1*s); atomicAdd(&f[3*r+2], -v2*s);
  atomicAdd(&f[3*c+0],  v0*s); atomicAdd(&f[3*c+1],  v1*s); atomicAdd(&f[3*c+2],  v2*s);
}

// ---------------------------------------------------------------------------
extern "C" void kernel_launch(void* const* d_in, const int* in_sizes, int n_in,
                              void* d_out, int out_size, void* d_ws, size_t ws_size,
                              hipStream_t stream)
{
  const int N = in_sizes[0];
  const int E = in_sizes[2]/2;
  const int L = 6;
  const int* z        = (const int*)d_in[0];
  const float* pos    = (const float*)d_in[1];
  const int* ei       = (const int*)d_in[2];
  const float* offset = (const float*)d_in[3];
  const float* cell   = (const float*)d_in[4];
  const float* emb    = (const float*)d_in[5];
  const float* mlp_w1 = (const float*)d_in[6];
  const float* mlp_b1 = (const float*)d_in[7];
  const float* mlp_w2 = (const float*)d_in[8];
  const float* mlp_b2 = (const float*)d_in[9];
  const float* conv_w1= (const float*)d_in[10];
  const float* conv_w2= (const float*)d_in[11];
  const float* conv_b2= (const float*)d_in[12];
  const float* lin_w  = (const float*)d_in[13];
  const float* lin_b  = (const float*)d_in[14];
  const float* out1_w = (const float*)d_in[15];
  const float* out1_b = (const float*)d_in[16];
  const float* out2_w = (const float*)d_in[17];
  const float* out2_b = (const float*)d_in[18];
  float* out = (float*)d_out;

  char* wp = (char*)d_ws;
  auto alloc = [&](size_t bytes)->char*{ char* p = wp; wp += (bytes + 255) & ~(size_t)255; return p; };
  float* wbuf = (float*)alloc((size_t)E*4);
  float* Cbuf = (float*)alloc((size_t)E*4);
  float* dCb  = (float*)alloc((size_t)E*4);
  float* dwb  = (float*)alloc((size_t)E*4);
  float* xh   = (float*)alloc((size_t)L*N*128*4);
  float* mbuf = (float*)alloc((size_t)L*N*128*4);
  float* ubuf = (float*)alloc((size_t)N*64*4);
  float* hbuf = (float*)alloc((size_t)N*128*4);
  float* Gbuf = (float*)alloc((size_t)N*128*4);
  float* bufA = (float*)alloc((size_t)N*128*4);
  float* bufB = (float*)alloc((size_t)N*128*4);
  float* bufC = (float*)alloc((size_t)N*128*4);   // dxh
  float* aggb = (float*)alloc((size_t)N*128*4);
  __bf16* W1t = (__bf16*)alloc((size_t)L*8192*2);
  __bf16* W2t = (__bf16*)alloc((size_t)L*16384*2);
  __bf16* W2c = (__bf16*)alloc((size_t)L*16384*2);
  __bf16* W1c = (__bf16*)alloc((size_t)L*8192*2);

  const int egrid = (E+255)/256;
  const int eg64 = (E+63)/64;
  const int ng = (N+127)/128;
  const int wtotal = L*49152;

  hipMemsetAsync(d_out, 0, (size_t)out_size*4, stream);
  convw_k<<<(wtotal+255)/256,256,0,stream>>>(mlp_w1, mlp_w2, W1t, W2t, W2c, W1c, wtotal);
  edge_geom_k<<<egrid,256,0,stream>>>(pos, ei, offset, cell, wbuf, Cbuf, E);
  embed_k<<<(N*128+255)/256,256,0,stream>>>(emb, z, hbuf, N*128);

  // ---------------- forward ----------------
  for (int i=0;i<L;i++){
    const float* b1i = mlp_b1 + (size_t)i*128;
    const float* b2i = mlp_b2 + (size_t)i*128;
    const float* cw1i= conv_w1+ (size_t)i*128*128;
    const float* cw2i= conv_w2+ (size_t)i*128*128;
    const float* cb2i= conv_b2+ (size_t)i*128;
    const float* lwi = lin_w  + (size_t)i*128*128;
    const float* lbi = lin_b  + (size_t)i*128;
    float* xhi = xh   + (size_t)i*N*128;
    float* mi  = mbuf + (size_t)i*N*128;

    gemm_k<128,128,false,0,false,0,false><<<ng,256,0,stream>>>(
      hbuf, 128, nullptr, nullptr, cw1i, 128, 128, nullptr, nullptr, nullptr, xhi, N);
    hipMemsetAsync(aggb, 0, (size_t)N*128*4, stream);
    fwd_edge_k<<<eg64,256,0,stream>>>(
      wbuf, Cbuf, ei, E, W1t + (size_t)i*8192, b1i, W2t + (size_t)i*16384, b2i, xhi, aggb);
    gemm_k<128,128,false,0,true,0,false><<<ng,256,0,stream>>>(
      aggb, 128, nullptr, nullptr, cw2i, 128, 128, cb2i, nullptr, nullptr, mi, N);
    gemm_k<128,128,false,1,true,0,true><<<ng,256,0,stream>>>(
      mi, 128, nullptr, nullptr, lwi, 128, 128, lbi, hbuf, nullptr, hbuf, N);
  }

  // head: u = h@o1+b ; E = sum ssp(u)@o2 + N*o2b ; G = (o2*sig(u))@o1^T
  gemm_k<128,64,false,0,true,0,false><<<ng,256,0,stream>>>(
    hbuf, 128, nullptr, nullptr, out1_w, 128, 64, out1_b, nullptr, nullptr, ubuf, N);
  head_k<<<(N+255)/256,256,0,stream>>>(ubuf, out2_w, out2_b, out, N);
  gemm_k<64,128,true,3,false,0,false><<<ng,256,0,stream>>>(
    ubuf, 64, nullptr, out2_w, out1_w, 64, 128, nullptr, nullptr, nullptr, Gbuf, N);

  // ---------------- backward ----------------
  for (int i=L-1;i>=0;i--){
    const float* b1i = mlp_b1 + (size_t)i*128;
    const float* b2i = mlp_b2 + (size_t)i*128;
    const float* cw1i= conv_w1+ (size_t)i*128*128;
    const float* cw2i= conv_w2+ (size_t)i*128*128;
    const float* lwi = lin_w  + (size_t)i*128*128;
    float* xhi = xh   + (size_t)i*N*128;
    float* mi  = mbuf + (size_t)i*N*128;
    int first = (i==L-1) ? 0 : 1;

    gemm_k<128,128,true,0,false,0,false><<<ng,256,0,stream>>>(
      Gbuf, 128, nullptr, nullptr, lwi, 128, 128, nullptr, nullptr, nullptr, bufA, N);
    gemm_k<128,128,true,2,false,0,false><<<ng,256,0,stream>>>(
      bufA, 128, mi, nullptr, cw2i, 128, 128, nullptr, nullptr, nullptr, bufB, N);
    hipMemsetAsync(bufC, 0, (size_t)N*128*4, stream);
    bwd_edge_k<<<eg64,256,0,stream>>>(
      wbuf, Cbuf, ei, E,
      W1t + (size_t)i*8192, b1i, W2t + (size_t)i*16384, b2i,
      W2c + (size_t)i*16384, W1c + (size_t)i*8192,
      bufB, xhi, bufC, dCb, dwb, first);
    gemm_k<128,128,true,0,false,0,true><<<ng,256,0,stream>>>(
      bufC, 128, nullptr, nullptr, cw1i, 128, 128, nullptr, Gbuf, nullptr, Gbuf, N);
  }

  force_k<<<egrid,256,0,stream>>>(dwb, dCb, wbuf, pos, ei, offset, cell, out+1, E);
}